// Round 9
// baseline (350.306 us; speedup 1.0000x reference)
//
#include <hip/hip_runtime.h>
#include <cstdint>
#include <cmath>

typedef __bf16 bf16x8 __attribute__((ext_vector_type(8)));
typedef float  f32x4  __attribute__((ext_vector_type(4)));

#define DEVI __device__ __forceinline__

#define SEQ 4096
#define NH 8
#define NKV 4
#define HD 256
#define WIN 1024

DEVI void gload16(const void* g, void* l) {
  __builtin_amdgcn_global_load_lds((const __attribute__((address_space(1))) void*)g,
                                   (__attribute__((address_space(3))) void*)l,
                                   16, 0, 0);
}

DEVI bf16x8 ld8f(const float* p) {
  const f32x4 a = *(const f32x4*)p;
  const f32x4 b = *(const f32x4*)(p + 4);
  bf16x8 r;
#pragma unroll
  for (int j = 0; j < 4; ++j) { r[j] = (__bf16)a[j]; r[4 + j] = (__bf16)b[j]; }
  return r;
}

DEVI void st1(float* p, float v)  { *p = v; }
DEVI void st1(__bf16* p, float v) { *p = (__bf16)v; }

// raw barrier (no vmcnt(0) drain, unlike __syncthreads) + compiler memory fence
DEVI void barx() {
  asm volatile("" ::: "memory");
  __builtin_amdgcn_s_barrier();
  asm volatile("" ::: "memory");
}

// ---------------------------------------------------------------------------
// fp32 -> bf16 conversion. Wq/Wk/Wv concatenated into one 4096x2048 buffer.
// ---------------------------------------------------------------------------
__global__ __launch_bounds__(256)
void cvt_all(const float* __restrict__ x,  const float* __restrict__ wq,
             const float* __restrict__ wk, const float* __restrict__ wv,
             const float* __restrict__ wo,
             __bf16* __restrict__ xb, __bf16* __restrict__ wqkvb,
             __bf16* __restrict__ wob) {
  const size_t g = (size_t)blockIdx.x * 256 + threadIdx.x;
  const float* src; __bf16* dst; size_t off;
  if      (g < 1048576) { src = x;  dst = xb;               off = g; }
  else if (g < 1572864) { src = wq; dst = wqkvb;            off = g - 1048576; }
  else if (g < 1835008) { src = wk; dst = wqkvb + 4194304;  off = g - 1572864; }
  else if (g < 2097152) { src = wv; dst = wqkvb + 6291456;  off = g - 1835008; }
  else                  { src = wo; dst = wob;              off = g - 2097152; }
  *(bf16x8*)(dst + off * 8) = ld8f(src + off * 8);
}

// ---------------------------------------------------------------------------
// QKV GEMM + fused RMSNorm/RoPE epilogue.
// K-loop is the validated gemm256<256> 4-phase schedule (r3-r8), UNTOUCHED.
// Epilogue: with BN=256, each block's column band is exactly one head
// (colT 0..7 = Q heads, 8..11 = K heads, 12..15 = V heads), so the RMSNorm
// reduction (over head dim 256) is block-local:
//   - per-row sum-of-squares: 4x shfl_xor over the wave's 64 cols, then a
//     [256][4] LDS table across the 4 wn waves (2 extra barriers).
//     LDS reuse is safe: epilogue starts after own vmcnt(0) (all gload_lds
//     drained) and a barrier at which every wave has already consumed its
//     last ds_reads (lgkm waited before final MFMAs).
//   - RoPE pair (d, d^1) lives in the adjacent l15 lane -> __shfl_xor(nv,1).
//   - fp32 acc -> norm -> rope -> single bf16 store (removes the bf16
//     round-trip the standalone norm kernel had).
// V band (colT >= 12): plain bf16 store; transposed by v_transpose.
// ---------------------------------------------------------------------------
__global__ __launch_bounds__(512, 2)
void gemm_qkv(const __bf16* __restrict__ A, const __bf16* __restrict__ B,
              __bf16* __restrict__ C, const float* __restrict__ qnw,
              const float* __restrict__ knw, const int* __restrict__ pos,
              int N, int K) {
  constexpr int MF    = 8;
  constexpr int MH    = 4;
  constexpr int AUNIT = 16384;         // 256 rows * 64 B
  constexpr int ASZ   = 4 * AUNIT;
  constexpr int VMC   = 8;             // 2*AI + 4, AI = 2
  __shared__ char lds[ASZ + 65536];

  const int tid  = threadIdx.x;
  const int lane = tid & 63;
  const int wave = tid >> 6;
  const int l15  = lane & 15;
  const int l4   = lane >> 4;
  const int wm   = wave >> 2;
  const int wn   = wave & 3;

  const int lin  = blockIdx.x;
  const int xcd  = lin & 7;
  const int kk   = lin >> 3;
  const int nTn  = N >> 8;
  const int rowT = kk % 16;
  const int colT = xcd * (nTn >> 3) + kk / 16;
  const int row0 = rowT * 256;
  const int col0 = colT << 8;

  const int srow = tid >> 2;
  const int scol = ((tid & 3) ^ ((tid >> 3) & 3)) << 3;
  const __bf16* Asrc = A + (size_t)(row0 + srow) * K + scol;
  const __bf16* Bsrc = B + (size_t)(col0 + srow) * K + scol;

  const int swz  = (l4 ^ ((l15 >> 1) & 3)) << 4;
  const int aoff = (wm * 128 + l15) * 64 + swz;
  const int boff = ((wn << 6) + l15) * 64 + swz;

  auto stA = [&](int kx, int h) {
    int k0 = kx << 6; if (k0 >= K) k0 = 0;
    const __bf16* s = Asrc + k0 + (h << 5);
    char* d = lds + ((kx & 1) * 2 + h) * AUNIT + wave * 1024;
#pragma unroll
    for (int i = 0; i < 2; ++i)
      gload16(s + (size_t)(i << 7) * K, d + i * 8192);
  };
  auto stB = [&](int kx, int h) {
    int k0 = kx << 6; if (k0 >= K) k0 = 0;
    const __bf16* s = Bsrc + k0 + (h << 5);
    char* d = lds + ASZ + ((kx & 1) * 2 + h) * 16384 + wave * 1024;
#pragma unroll
    for (int i = 0; i < 2; ++i)
      gload16(s + (size_t)(i << 7) * K, d + i * 8192);
  };

  f32x4 acc[MF][4] = {};

  stA(0, 0); stB(0, 0); stA(0, 1); stB(0, 1); stA(1, 0); stB(1, 0);
  asm volatile("s_waitcnt vmcnt(%0)" :: "i"(VMC) : "memory");
  barx();

  const int NT = K >> 6;
  for (int kt = 0; kt < NT; ++kt) {
    const int bb = (kt & 1) * 2;
    bf16x8 bfr[4];
    bf16x8 af[MH];

    auto rd = [&](int h, int mg, bool readB) {
      const char* pa = lds + (bb + h) * AUNIT + aoff;
#pragma unroll
      for (int m = 0; m < MH; ++m)
        af[m] = *(const bf16x8*)(pa + ((mg * MH + m) << 10));
      if (readB) {
        const char* pb = lds + ASZ + (bb + h) * 16384 + boff;
#pragma unroll
        for (int n = 0; n < 4; ++n)
          bfr[n] = *(const bf16x8*)(pb + (n << 10));
      }
    };
    auto mm = [&](int mg) {
      barx();
      __builtin_amdgcn_s_setprio(1);
#pragma unroll
      for (int m = 0; m < MH; ++m)
#pragma unroll
        for (int n = 0; n < 4; ++n)
          acc[mg * MH + m][n] =
              __builtin_amdgcn_mfma_f32_16x16x32_bf16(af[m], bfr[n], acc[mg * MH + m][n], 0, 0, 0);
      __builtin_amdgcn_s_setprio(0);
    };

    // p0
    rd(0, 0, true);
    stA(kt + 1, 1);
    mm(0);
    // p1
    rd(0, 1, false);
    stB(kt + 1, 1);
    asm volatile("s_waitcnt vmcnt(%0)" :: "i"(VMC) : "memory");
    mm(1);
    // p2
    rd(1, 0, true);
    stA(kt + 2, 0);
    mm(0);
    // p3
    rd(1, 1, false);
    stB(kt + 2, 0);
    asm volatile("s_waitcnt vmcnt(%0)" :: "i"(VMC) : "memory");
    mm(1);
  }
  asm volatile("s_waitcnt vmcnt(0)" ::: "memory");

  if (colT < 12) {
    // ---- fused RMSNorm + RoPE (Q: colT<8 with qnw, K: 8..11 with knw) ----
    barx();                                    // LDS free for reuse (see hdr)
    float* ssb = (float*)lds;                  // [256 rows][4 wn]
#pragma unroll
    for (int mf = 0; mf < MF; ++mf) {
#pragma unroll
      for (int reg = 0; reg < 4; ++reg) {
        float q = 0.f;
#pragma unroll
        for (int n = 0; n < 4; ++n) { const float v = acc[mf][n][reg]; q += v * v; }
        q += __shfl_xor(q, 1); q += __shfl_xor(q, 2);
        q += __shfl_xor(q, 4); q += __shfl_xor(q, 8);
        if (l15 == 0) {
          const int lr = wm * 128 + (mf >> 2) * 64 + (mf & 3) * 16 + (l4 << 2) + reg;
          ssb[lr * 4 + wn] = q;
        }
      }
    }
    barx();
    const float* w = (colT < 8) ? qnw : knw;
    float wv4[4], fr4[4];
#pragma unroll
    for (int n = 0; n < 4; ++n) {
      const int d = (wn << 6) + n * 16 + l15;  // head dim of this element
      wv4[n] = w[d];
      fr4[n] = exp2f(-(float)(d & 127) * 0.103810253f);
    }
    const float sgn = (l15 & 1) ? 1.f : -1.f;  // even d: -x[d+1]; odd: +x[d-1]
#pragma unroll
    for (int mf = 0; mf < MF; ++mf) {
#pragma unroll
      for (int reg = 0; reg < 4; ++reg) {
        const int lr = wm * 128 + (mf >> 2) * 64 + (mf & 3) * 16 + (l4 << 2) + reg;
        const float ss = ssb[lr * 4 + 0] + ssb[lr * 4 + 1]
                       + ssb[lr * 4 + 2] + ssb[lr * 4 + 3];
        const float rms = rsqrtf(ss * (1.0f / 256.0f) + 1e-6f);
        const float p = (float)pos[row0 + lr];
        __bf16* crow = C + (size_t)(row0 + lr) * N + col0 + (wn << 6) + l15;
#pragma unroll
        for (int n = 0; n < 4; ++n) {
          const float nv = acc[mf][n][reg] * rms * wv4[n];
          const float pk = __shfl_xor(nv, 1);  // partner dim d^1, same row
          float s, c;
          sincosf(p * fr4[n], &s, &c);
          crow[n * 16] = (__bf16)(nv * c + sgn * pk * s);
        }
      }
    }
  } else {
    // ---- V band: plain store (transposed later by v_transpose) ----
#pragma unroll
    for (int mf = 0; mf < MF; ++mf) {
      const int rb = row0 + wm * 128 + (mf >> 2) * 64 + (mf & 3) * 16 + (l4 << 2);
#pragma unroll
      for (int reg = 0; reg < 4; ++reg) {
        __bf16* crow = C + (size_t)(rb + reg) * N + col0 + (wn << 6) + l15;
#pragma unroll
        for (int n = 0; n < 4; ++n) crow[n << 4] = (__bf16)acc[mf][n][reg];
      }
    }
  }
}

// ---------------------------------------------------------------------------
// GEMM 2-phase — out-proj (BM=128). Proven best in rounds 4/5 (~48 µs).
// ---------------------------------------------------------------------------
template <int BM, typename TC>
__global__ __launch_bounds__(512, 2)
void gemm2ph(const __bf16* __restrict__ A, const __bf16* __restrict__ B,
             TC* __restrict__ C, int N, int K) {
  constexpr int AI    = BM / 128;
  constexpr int MF    = BM / 32;
  constexpr int AUNIT = BM * 64;
  constexpr int ASZ   = 4 * AUNIT;
  constexpr int VMC   = 2 * (AI + 2);
  __shared__ char lds[ASZ + 65536];

  const int tid  = threadIdx.x;
  const int lane = tid & 63;
  const int wave = tid >> 6;
  const int l15  = lane & 15;
  const int l4   = lane >> 4;
  const int wm   = wave >> 2;
  const int wn   = wave & 3;

  constexpr int nTm = 4096 / BM;
  const int lin  = blockIdx.x;
  const int xcd  = lin & 7;
  const int kk   = lin >> 3;
  const int nTn  = N >> 8;
  const int rowT = kk % nTm;
  const int colT = xcd * (nTn >> 3) + kk / nTm;
  const int row0 = rowT * BM;
  const int col0 = colT << 8;

  const int srow = tid >> 2;
  const int scol = ((tid & 3) ^ ((tid >> 3) & 3)) << 3;
  const __bf16* Asrc = A + (size_t)(row0 + srow) * K + scol;
  const __bf16* Bsrc = B + (size_t)(col0 + srow) * K + scol;

  const int swz  = (l4 ^ ((l15 >> 1) & 3)) << 4;
  const int aoff = (wm * (BM / 2) + l15) * 64 + swz;
  const int boff = ((wn << 6) + l15) * 64 + swz;

  auto stA = [&](int kx, int h, int b) {
    int k0 = kx << 6; if (k0 >= K) k0 = 0;
    const __bf16* s = Asrc + k0 + (h << 5);
    char* d = lds + (b * 2 + h) * AUNIT + wave * 1024;
#pragma unroll
    for (int i = 0; i < AI; ++i)
      gload16(s + (size_t)(i << 7) * K, d + i * 8192);
  };
  auto stB = [&](int kx, int h, int b) {
    int k0 = kx << 6; if (k0 >= K) k0 = 0;
    const __bf16* s = Bsrc + k0 + (h << 5);
    char* d = lds + ASZ + (b * 2 + h) * 16384 + wave * 1024;
#pragma unroll
    for (int i = 0; i < 2; ++i)
      gload16(s + (size_t)(i << 7) * K, d + i * 8192);
  };

  f32x4 acc[MF][4] = {};

  stA(0, 0, 0); stB(0, 0, 0);
  stA(0, 1, 0); stB(0, 1, 0);
  stA(1, 0, 1); stB(1, 0, 1);

  const int NT = K >> 6;
  for (int kt = 0; kt < NT; ++kt) {
    const int b = kt & 1, nb = b ^ 1;
#pragma unroll
    for (int half = 0; half < 2; ++half) {
      asm volatile("s_waitcnt vmcnt(%0)" :: "i"(VMC) : "memory");
      barx();
      bf16x8 af[4], ag[4], bfr[4];
      const char* pa = lds + (b * 2 + half) * AUNIT + aoff;
      const char* pb = lds + ASZ + (b * 2 + half) * 16384 + boff;
#pragma unroll
      for (int m = 0; m < 4; ++m) af[m] = *(const bf16x8*)(pa + (m << 10));
#pragma unroll
      for (int n = 0; n < 4; ++n) bfr[n] = *(const bf16x8*)(pb + (n << 10));
      if constexpr (BM == 256) {
#pragma unroll
        for (int m = 0; m < 4; ++m) ag[m] = *(const bf16x8*)(pa + 4096 + (m << 10));
      }
      if (half == 0) { stA(kt + 1, 1, nb); stB(kt + 1, 1, nb); }
      else           { stA(kt + 2, 0, b);  stB(kt + 2, 0, b);  }
      __builtin_amdgcn_s_setprio(1);
#pragma unroll
      for (int m = 0; m < 4; ++m)
#pragma unroll
        for (int n = 0; n < 4; ++n)
          acc[m][n] = __builtin_amdgcn_mfma_f32_16x16x32_bf16(af[m], bfr[n], acc[m][n], 0, 0, 0);
      if constexpr (BM == 256) {
#pragma unroll
        for (int m = 0; m < 4; ++m)
#pragma unroll
          for (int n = 0; n < 4; ++n)
            acc[4 + m][n] = __builtin_amdgcn_mfma_f32_16x16x32_bf16(ag[m], bfr[n], acc[4 + m][n], 0, 0, 0);
      }
      __builtin_amdgcn_s_setprio(0);
    }
  }

#pragma unroll
  for (int mf = 0; mf < MF; ++mf) {
    const int rb = row0 + wm * (BM / 2) + (mf >> 2) * 64 + (mf & 3) * 16 + (l4 << 2);
#pragma unroll
    for (int reg = 0; reg < 4; ++reg) {
      TC* crow = C + (size_t)(rb + reg) * N + col0 + (wn << 6) + l15;
#pragma unroll
      for (int n = 0; n < 4; ++n) st1(crow + (n << 4), acc[mf][n][reg]);
    }
  }
}

// ---------------------------------------------------------------------------
// V-transpose only (norm/rope now fused into gemm_qkv's epilogue).
// ---------------------------------------------------------------------------
__global__ __launch_bounds__(256)
void v_transpose(const __bf16* __restrict__ qkv, __bf16* __restrict__ Vt) {
  __shared__ __bf16 tile[64][72];
  const int b   = blockIdx.x;               // 0..1023
  const int tid = threadIdx.x;
  const int tb  = (b & 63) * 64;
  const int yy  = b >> 6;                   // 0..15
  const int kvh = yy >> 2;
  const int db  = (yy & 3) * 64;
#pragma unroll
  for (int i = 0; i < 2; ++i) {
    const int s = i * 256 + tid;
    const int r = s >> 3, c = (s & 7) * 8;
    bf16x8 val = *(const bf16x8*)(qkv + (size_t)(tb + r) * 4096 + 3072 + kvh * HD + db + c);
#pragma unroll
    for (int j = 0; j < 8; ++j) tile[r][c + j] = val[j];
  }
  __syncthreads();
#pragma unroll
  for (int i = 0; i < 2; ++i) {
    const int s = i * 256 + tid;
    const int r = s >> 3, c = (s & 7) * 8;
    bf16x8 outv;
#pragma unroll
    for (int j = 0; j < 8; ++j) outv[j] = tile[c + j][r];
    *(bf16x8*)(Vt + (size_t)(kvh * HD + db + r) * SEQ + tb + c) = outv;
  }
}

// ---------------------------------------------------------------------------
// Sliding-window flash attention — r5 known-best structure, verbatim
// (2-slot dbuf, vmcnt(8) gate, T2 swizzle, head-per-XCD, fast-path softmax;
// measured 64.4 µs). r8's 4-chain QK was neutral (65.1) — reverted.
// ---------------------------------------------------------------------------
__global__ __launch_bounds__(256, 2)
void attn_fwd(const __bf16* __restrict__ qkv, const __bf16* __restrict__ Vt,
              __bf16* __restrict__ Y) {
  __shared__ char klds[2][16384];      // [slot][32 key][32 dim] rows of 64B, swz
  __shared__ char vlds[2][16384];      // [slot][256 dim][32 key] rows of 64B, swz
  __shared__ __bf16 Ps[4][16][40];     // per-wave P (padded rows)
  const int tid  = threadIdx.x;
  const int lane = tid & 63;
  const int wave = tid >> 6;
  const int l15  = lane & 15;
  const int l4   = lane >> 4;
  const int lin  = blockIdx.x;
  const int head = lin & 7;            // head-per-XCD pinning
  const int q0   = (lin >> 3) * 64;
  const int kvh  = head >> 1;
  const int qw   = q0 + wave * 16;

  // Q fragments: A[m=lane&15][k=(lane>>4)*8+j]; pre-scale 1/16 (exact pow2)
  bf16x8 qf[8];
  const __bf16* qrow = qkv + (size_t)(qw + l15) * 4096 + head * HD;
#pragma unroll
  for (int ks = 0; ks < 8; ++ks) {
    bf16x8 t = *(const bf16x8*)(qrow + ks * 32 + l4 * 8);
#pragma unroll
    for (int j = 0; j < 8; ++j) t[j] = (__bf16)((float)t[j] * 0.0625f);
    qf[ks] = t;
  }

  f32x4 o[16] = {};
  float l_run[4] = {0.f, 0.f, 0.f, 0.f};

  int lo = q0 - (WIN - 1); if (lo < 0) lo = 0;
  const int kt0 = lo >> 5;
  const int kt1 = (q0 + 63) >> 5;      // >= kt0+1 always (>=2 tiles)
  const int kbmax = kt1 << 5;

  const int skey = (tid >> 2) & 31;                 // K: key row
  const int sdim = tid >> 2;                        // V: dim row (+ i*64)
  const int sg   = (tid & 3) ^ ((tid >> 3) & 3);    // swizzled source col16
  const int sth  = tid >> 7;

  auto stK = [&](int kt, int b) {
    int kb = kt << 5; if (kb > kbmax) kb = kbmax;   // clamped dummy re-issue
    const __bf16* s = qkv + (size_t)(kb + skey) * 4096 + 2048 + kvh * HD
                          + sth * 32 + sg * 8;
    char* d = klds[b] + wave * 1024;
#pragma unroll
    for (int i = 0; i < 4; ++i)
      gload16(s + i * 64, d + i * 4096);
  };
  auto stV = [&](int kt, int b) {
    int kb = kt << 5; if (kb > kbmax) kb = kbmax;
    const __bf16* s = Vt + ((size_t)kvh * HD + sdim) * SEQ + kb + sg * 8;
    char* d = vlds[b] + wave * 1024;
#pragma unroll
    for (int i = 0; i < 4; ++i)
      gload16(s + (size_t)i * 64 * SEQ, d + i * 4096);
  };

  stK(kt0, 0);     stV(kt0, 0);
  stK(kt0 + 1, 1); stV(kt0 + 1, 1);

  const int rswz = (l4 ^ ((l15 >> 1) & 3)) << 4;

  for (int kt = kt0; kt <= kt1; ++kt) {
    const int p  = (kt - kt0) & 1;
    const int kb = kt << 5;
    asm volatile("s_waitcnt vmcnt(8)" ::: "memory");
    barx();

    // S = (Q/16) K^T   (32 keys: kn = 0..1)
    const char* kbase = klds[p];
    f32x4 s_acc[2] = {};
    __builtin_amdgcn_s_setprio(1);
#pragma unroll
    for (int kn = 0; kn < 2; ++kn) {
#pragma unroll
      for (int ks = 0; ks < 8; ++ks) {
        bf16x8 kf = *(const bf16x8*)(kbase + (ks * 32 + kn * 16 + l15) * 64 + rswz);
        s_acc[kn] = __builtin_amdgcn_mfma_f32_16x16x32_bf16(qf[ks], kf, s_acc[kn], 0, 0, 0);
      }
    }
    __builtin_amdgcn_s_setprio(0);

    // fixed-max softmax: p = exp(min(s,34)-34); masked -> 0
    // Fast path (wave-uniform): tile fully inside causal+window.
    if ((kb + 31 <= qw) && (kb >= qw - 1008)) {
#pragma unroll
      for (int reg = 0; reg < 4; ++reg) {
        const int r = l4 * 4 + reg;
        float ps = 0.f;
#pragma unroll
        for (int kn = 0; kn < 2; ++kn) {
          const float pv = __expf(fminf(s_acc[kn][reg], 34.f) - 34.f);
          ps += pv;
          Ps[wave][r][kn * 16 + l15] = (__bf16)pv;
        }
        l_run[reg] += ps;
      }
    } else {
#pragma unroll
      for (int reg = 0; reg < 4; ++reg) {
        const int r  = l4 * 4 + reg;
        const int qg = qw + r;
        float ps = 0.f;
#pragma unroll
        for (int kn = 0; kn < 2; ++kn) {
          const int kg = kb + kn * 16 + l15;
          const bool ok = (kg <= qg) && (kg > qg - WIN);
          const float pv = ok ? __expf(fminf(s_acc[kn][reg], 34.f) - 34.f) : 0.f;
          ps += pv;
          Ps[wave][r][kn * 16 + l15] = (__bf16)pv;
        }
        l_run[reg] += ps;
      }
    }

    // O += P V   (Ps per-wave; intra-wave LDS ordering needs no barrier)
    const char* vbase = vlds[p];
    bf16x8 pf = *(const bf16x8*)&Ps[wave][l15][l4 * 8];
    __builtin_amdgcn_s_setprio(1);
#pragma unroll
    for (int dn = 0; dn < 16; ++dn) {
      bf16x8 vf = *(const bf16x8*)(vbase + (dn * 16 + l15) * 64 + rswz);
      o[dn] = __builtin_amdgcn_mfma_f32_16x16x32_bf16(pf, vf, o[dn], 0, 0, 0);
    }
    __builtin_amdgcn_s_setprio(0);

    // retire buf p readers, then refill it with tile kt+2
    barx();
    stK(kt + 2, p);
    stV(kt + 2, p);
  }
  // no DMA in flight at exit (LDS may be reassigned to the next block)
  asm volatile("s_waitcnt vmcnt(0)" ::: "memory");

  // epilogue: reduce l across the 16 lanes sharing each row, then scale
#pragma unroll
  for (int reg = 0; reg < 4; ++reg) {
#pragma unroll
    for (int off = 1; off < 16; off <<= 1)
      l_run[reg] += __shfl_xor(l_run[reg], off);
    const float inv = 1.0f / l_run[reg];
    const int q = qw + l4 * 4 + reg;
    __bf16* yrow = Y + ((size_t)q * NH + head) * HD + l15;
#pragma unroll
    for (int dn = 0; dn < 16; ++dn)
      yrow[dn * 16] = (__bf16)(o[dn][reg] * inv);
  }
}

// ---------------------------------------------------------------------------
extern "C" void kernel_launch(void* const* d_in, const int* in_sizes, int n_in,
                              void* d_out, int out_size, void* d_ws, size_t ws_size,
                              hipStream_t stream) {
  (void)in_sizes; (void)n_in; (void)out_size; (void)ws_size;
  const float* x   = (const float*)d_in[0];
  const int*   pos = (const int*)d_in[1];
  const float* Wq  = (const float*)d_in[2];
  const float* Wk  = (const float*)d_in[3];
  const float* Wv  = (const float*)d_in[4];
  const float* Wo  = (const float*)d_in[5];
  const float* qw  = (const float*)d_in[6];
  const float* kw  = (const float*)d_in[7];
  float* out = (float*)d_out;

  char* ws = (char*)d_ws;
  const size_t MB = 1024 * 1024;
  __bf16* qkv_ws = (__bf16*)(ws);             // 32 MiB  [4096][4096]
  __bf16* vt_ws  = (__bf16*)(ws + 32 * MB);   //  8 MiB  [4][256][4096]
  __bf16* y_ws   = (__bf16*)(ws + 40 * MB);   // 16 MiB  [4096][2048]
  __bf16* xb     = (__bf16*)(ws + 56 * MB);   // 16 MiB
  __bf16* wqkvb  = (__bf16*)(ws + 72 * MB);   // 16 MiB  [4096][2048]
  __bf16* wob    = (__bf16*)(ws + 88 * MB);   //  8 MiB  (total 96 MiB)

  cvt_all<<<dim3(10240), dim3(256), 0, stream>>>(x, Wq, Wk, Wv, Wo, xb, wqkvb, wob);
  gemm_qkv<<<dim3(256), dim3(512), 0, stream>>>(xb, wqkvb, qkv_ws, qw, kw, pos, 4096, 2048);
  v_transpose<<<dim3(1024), dim3(256), 0, stream>>>(qkv_ws, vt_ws);
  attn_fwd<<<dim3(512), dim3(256), 0, stream>>>(qkv_ws, vt_ws, y_ws);
  gemm2ph<128, float><<<dim3(256), dim3(512), 0, stream>>>(y_ws, wob, out, 2048, 2048);
}

// Round 10
// 348.657 us; speedup vs baseline: 1.0047x; 1.0047x over previous
//
#include <hip/hip_runtime.h>
#include <cstdint>
#include <cmath>

typedef __bf16 bf16x8 __attribute__((ext_vector_type(8)));
typedef float  f32x4  __attribute__((ext_vector_type(4)));

#define DEVI __device__ __forceinline__

#define SEQ 4096
#define NH 8
#define NKV 4
#define HD 256
#define WIN 1024

DEVI void gload16(const void* g, void* l) {
  __builtin_amdgcn_global_load_lds((const __attribute__((address_space(1))) void*)g,
                                   (__attribute__((address_space(3))) void*)l,
                                   16, 0, 0);
}

DEVI bf16x8 ld8f(const float* p) {
  const f32x4 a = *(const f32x4*)p;
  const f32x4 b = *(const f32x4*)(p + 4);
  bf16x8 r;
#pragma unroll
  for (int j = 0; j < 4; ++j) { r[j] = (__bf16)a[j]; r[4 + j] = (__bf16)b[j]; }
  return r;
}

DEVI void st1(float* p, float v)  { *p = v; }
DEVI void st1(__bf16* p, float v) { *p = (__bf16)v; }

// raw barrier (no vmcnt(0) drain, unlike __syncthreads) + compiler memory fence
DEVI void barx() {
  asm volatile("" ::: "memory");
  __builtin_amdgcn_s_barrier();
  asm volatile("" ::: "memory");
}

// ---------------------------------------------------------------------------
// fp32 -> bf16 conversion. Wq/Wk/Wv concatenated into one 4096x2048 buffer.
// ---------------------------------------------------------------------------
__global__ __launch_bounds__(256)
void cvt_all(const float* __restrict__ x,  const float* __restrict__ wq,
             const float* __restrict__ wk, const float* __restrict__ wv,
             const float* __restrict__ wo,
             __bf16* __restrict__ xb, __bf16* __restrict__ wqkvb,
             __bf16* __restrict__ wob) {
  const size_t g = (size_t)blockIdx.x * 256 + threadIdx.x;
  const float* src; __bf16* dst; size_t off;
  if      (g < 1048576) { src = x;  dst = xb;               off = g; }
  else if (g < 1572864) { src = wq; dst = wqkvb;            off = g - 1048576; }
  else if (g < 1835008) { src = wk; dst = wqkvb + 4194304;  off = g - 1572864; }
  else if (g < 2097152) { src = wv; dst = wqkvb + 6291456;  off = g - 1835008; }
  else                  { src = wo; dst = wob;              off = g - 2097152; }
  *(bf16x8*)(dst + off * 8) = ld8f(src + off * 8);
}

// ---------------------------------------------------------------------------
// QKV GEMM + fused RMSNorm/RoPE epilogue (r9 fusion, r10 store-burst fix).
// K-loop is the validated gemm256<256> 4-phase schedule (r3-r8), UNTOUCHED.
// r9 post-mortem: storing inside the per-element loop interleaved sincosf
// between the 4 stores of each 128B C-line -> L2 write-combining window
// closed -> partial-line RMW (WRITE 32.8->164MB, FETCH +32MB). Fix: compute
// ov[4] fully in registers, then issue the row's 4 stores back-to-back so
// the wave completes each 128B line in one burst (full-line dirty, no RMW).
// ---------------------------------------------------------------------------
__global__ __launch_bounds__(512, 2)
void gemm_qkv(const __bf16* __restrict__ A, const __bf16* __restrict__ B,
              __bf16* __restrict__ C, const float* __restrict__ qnw,
              const float* __restrict__ knw, const int* __restrict__ pos,
              int N, int K) {
  constexpr int MF    = 8;
  constexpr int MH    = 4;
  constexpr int AUNIT = 16384;         // 256 rows * 64 B
  constexpr int ASZ   = 4 * AUNIT;
  constexpr int VMC   = 8;             // 2*AI + 4, AI = 2
  __shared__ char lds[ASZ + 65536];

  const int tid  = threadIdx.x;
  const int lane = tid & 63;
  const int wave = tid >> 6;
  const int l15  = lane & 15;
  const int l4   = lane >> 4;
  const int wm   = wave >> 2;
  const int wn   = wave & 3;

  const int lin  = blockIdx.x;
  const int xcd  = lin & 7;
  const int kk   = lin >> 3;
  const int nTn  = N >> 8;
  const int rowT = kk % 16;
  const int colT = xcd * (nTn >> 3) + kk / 16;
  const int row0 = rowT * 256;
  const int col0 = colT << 8;

  const int srow = tid >> 2;
  const int scol = ((tid & 3) ^ ((tid >> 3) & 3)) << 3;
  const __bf16* Asrc = A + (size_t)(row0 + srow) * K + scol;
  const __bf16* Bsrc = B + (size_t)(col0 + srow) * K + scol;

  const int swz  = (l4 ^ ((l15 >> 1) & 3)) << 4;
  const int aoff = (wm * 128 + l15) * 64 + swz;
  const int boff = ((wn << 6) + l15) * 64 + swz;

  auto stA = [&](int kx, int h) {
    int k0 = kx << 6; if (k0 >= K) k0 = 0;
    const __bf16* s = Asrc + k0 + (h << 5);
    char* d = lds + ((kx & 1) * 2 + h) * AUNIT + wave * 1024;
#pragma unroll
    for (int i = 0; i < 2; ++i)
      gload16(s + (size_t)(i << 7) * K, d + i * 8192);
  };
  auto stB = [&](int kx, int h) {
    int k0 = kx << 6; if (k0 >= K) k0 = 0;
    const __bf16* s = Bsrc + k0 + (h << 5);
    char* d = lds + ASZ + ((kx & 1) * 2 + h) * 16384 + wave * 1024;
#pragma unroll
    for (int i = 0; i < 2; ++i)
      gload16(s + (size_t)(i << 7) * K, d + i * 8192);
  };

  f32x4 acc[MF][4] = {};

  stA(0, 0); stB(0, 0); stA(0, 1); stB(0, 1); stA(1, 0); stB(1, 0);
  asm volatile("s_waitcnt vmcnt(%0)" :: "i"(VMC) : "memory");
  barx();

  const int NT = K >> 6;
  for (int kt = 0; kt < NT; ++kt) {
    const int bb = (kt & 1) * 2;
    bf16x8 bfr[4];
    bf16x8 af[MH];

    auto rd = [&](int h, int mg, bool readB) {
      const char* pa = lds + (bb + h) * AUNIT + aoff;
#pragma unroll
      for (int m = 0; m < MH; ++m)
        af[m] = *(const bf16x8*)(pa + ((mg * MH + m) << 10));
      if (readB) {
        const char* pb = lds + ASZ + (bb + h) * 16384 + boff;
#pragma unroll
        for (int n = 0; n < 4; ++n)
          bfr[n] = *(const bf16x8*)(pb + (n << 10));
      }
    };
    auto mm = [&](int mg) {
      barx();
      __builtin_amdgcn_s_setprio(1);
#pragma unroll
      for (int m = 0; m < MH; ++m)
#pragma unroll
        for (int n = 0; n < 4; ++n)
          acc[mg * MH + m][n] =
              __builtin_amdgcn_mfma_f32_16x16x32_bf16(af[m], bfr[n], acc[mg * MH + m][n], 0, 0, 0);
      __builtin_amdgcn_s_setprio(0);
    };

    // p0
    rd(0, 0, true);
    stA(kt + 1, 1);
    mm(0);
    // p1
    rd(0, 1, false);
    stB(kt + 1, 1);
    asm volatile("s_waitcnt vmcnt(%0)" :: "i"(VMC) : "memory");
    mm(1);
    // p2
    rd(1, 0, true);
    stA(kt + 2, 0);
    mm(0);
    // p3
    rd(1, 1, false);
    stB(kt + 2, 0);
    asm volatile("s_waitcnt vmcnt(%0)" :: "i"(VMC) : "memory");
    mm(1);
  }
  asm volatile("s_waitcnt vmcnt(0)" ::: "memory");

  if (colT < 12) {
    // ---- fused RMSNorm + RoPE (Q: colT<8 with qnw, K: 8..11 with knw) ----
    barx();                                    // LDS free for reuse (see hdr)
    float* ssb = (float*)lds;                  // [256 rows][4 wn]
#pragma unroll
    for (int mf = 0; mf < MF; ++mf) {
#pragma unroll
      for (int reg = 0; reg < 4; ++reg) {
        float q = 0.f;
#pragma unroll
        for (int n = 0; n < 4; ++n) { const float v = acc[mf][n][reg]; q += v * v; }
        q += __shfl_xor(q, 1); q += __shfl_xor(q, 2);
        q += __shfl_xor(q, 4); q += __shfl_xor(q, 8);
        if (l15 == 0) {
          const int lr = wm * 128 + (mf >> 2) * 64 + (mf & 3) * 16 + (l4 << 2) + reg;
          ssb[lr * 4 + wn] = q;
        }
      }
    }
    barx();
    const float* w = (colT < 8) ? qnw : knw;
    float wv4[4], fr4[4];
#pragma unroll
    for (int n = 0; n < 4; ++n) {
      const int d = (wn << 6) + n * 16 + l15;  // head dim of this element
      wv4[n] = w[d];
      fr4[n] = exp2f(-(float)(d & 127) * 0.103810253f);
    }
    const float sgn = (l15 & 1) ? 1.f : -1.f;  // even d: -x[d+1]; odd: +x[d-1]
#pragma unroll
    for (int mf = 0; mf < MF; ++mf) {
#pragma unroll
      for (int reg = 0; reg < 4; ++reg) {
        const int lr = wm * 128 + (mf >> 2) * 64 + (mf & 3) * 16 + (l4 << 2) + reg;
        const float ss = ssb[lr * 4 + 0] + ssb[lr * 4 + 1]
                       + ssb[lr * 4 + 2] + ssb[lr * 4 + 3];
        const float rms = rsqrtf(ss * (1.0f / 256.0f) + 1e-6f);
        const float p = (float)pos[row0 + lr];
        // compute ALL 4 outputs first (trig+shfl done), THEN burst-store the
        // row's 128B line (4x32B back-to-back) — no RMW (r9 lesson).
        float ov[4];
#pragma unroll
        for (int n = 0; n < 4; ++n) {
          const float nv = acc[mf][n][reg] * rms * wv4[n];
          const float pk = __shfl_xor(nv, 1);  // partner dim d^1, same row
          float s, c;
          sincosf(p * fr4[n], &s, &c);
          ov[n] = nv * c + sgn * pk * s;
        }
        __bf16* crow = C + (size_t)(row0 + lr) * N + col0 + (wn << 6) + l15;
#pragma unroll
        for (int n = 0; n < 4; ++n) crow[n * 16] = (__bf16)ov[n];
      }
    }
  } else {
    // ---- V band: plain store (transposed later by v_transpose) ----
#pragma unroll
    for (int mf = 0; mf < MF; ++mf) {
      const int rb = row0 + wm * 128 + (mf >> 2) * 64 + (mf & 3) * 16 + (l4 << 2);
#pragma unroll
      for (int reg = 0; reg < 4; ++reg) {
        __bf16* crow = C + (size_t)(rb + reg) * N + col0 + (wn << 6) + l15;
#pragma unroll
        for (int n = 0; n < 4; ++n) crow[n << 4] = (__bf16)acc[mf][n][reg];
      }
    }
  }
}

// ---------------------------------------------------------------------------
// GEMM 2-phase — out-proj (BM=128). Proven best in rounds 4/5 (~48 µs).
// ---------------------------------------------------------------------------
template <int BM, typename TC>
__global__ __launch_bounds__(512, 2)
void gemm2ph(const __bf16* __restrict__ A, const __bf16* __restrict__ B,
             TC* __restrict__ C, int N, int K) {
  constexpr int AI    = BM / 128;
  constexpr int MF    = BM / 32;
  constexpr int AUNIT = BM * 64;
  constexpr int ASZ   = 4 * AUNIT;
  constexpr int VMC   = 2 * (AI + 2);
  __shared__ char lds[ASZ + 65536];

  const int tid  = threadIdx.x;
  const int lane = tid & 63;
  const int wave = tid >> 6;
  const int l15  = lane & 15;
  const int l4   = lane >> 4;
  const int wm   = wave >> 2;
  const int wn   = wave & 3;

  constexpr int nTm = 4096 / BM;
  const int lin  = blockIdx.x;
  const int xcd  = lin & 7;
  const int kk   = lin >> 3;
  const int nTn  = N >> 8;
  const int rowT = kk % nTm;
  const int colT = xcd * (nTn >> 3) + kk / nTm;
  const int row0 = rowT * BM;
  const int col0 = colT << 8;

  const int srow = tid >> 2;
  const int scol = ((tid & 3) ^ ((tid >> 3) & 3)) << 3;
  const __bf16* Asrc = A + (size_t)(row0 + srow) * K + scol;
  const __bf16* Bsrc = B + (size_t)(col0 + srow) * K + scol;

  const int swz  = (l4 ^ ((l15 >> 1) & 3)) << 4;
  const int aoff = (wm * (BM / 2) + l15) * 64 + swz;
  const int boff = ((wn << 6) + l15) * 64 + swz;

  auto stA = [&](int kx, int h, int b) {
    int k0 = kx << 6; if (k0 >= K) k0 = 0;
    const __bf16* s = Asrc + k0 + (h << 5);
    char* d = lds + (b * 2 + h) * AUNIT + wave * 1024;
#pragma unroll
    for (int i = 0; i < AI; ++i)
      gload16(s + (size_t)(i << 7) * K, d + i * 8192);
  };
  auto stB = [&](int kx, int h, int b) {
    int k0 = kx << 6; if (k0 >= K) k0 = 0;
    const __bf16* s = Bsrc + k0 + (h << 5);
    char* d = lds + ASZ + (b * 2 + h) * 16384 + wave * 1024;
#pragma unroll
    for (int i = 0; i < 2; ++i)
      gload16(s + (size_t)(i << 7) * K, d + i * 8192);
  };

  f32x4 acc[MF][4] = {};

  stA(0, 0, 0); stB(0, 0, 0);
  stA(0, 1, 0); stB(0, 1, 0);
  stA(1, 0, 1); stB(1, 0, 1);

  const int NT = K >> 6;
  for (int kt = 0; kt < NT; ++kt) {
    const int b = kt & 1, nb = b ^ 1;
#pragma unroll
    for (int half = 0; half < 2; ++half) {
      asm volatile("s_waitcnt vmcnt(%0)" :: "i"(VMC) : "memory");
      barx();
      bf16x8 af[4], ag[4], bfr[4];
      const char* pa = lds + (b * 2 + half) * AUNIT + aoff;
      const char* pb = lds + ASZ + (b * 2 + half) * 16384 + boff;
#pragma unroll
      for (int m = 0; m < 4; ++m) af[m] = *(const bf16x8*)(pa + (m << 10));
#pragma unroll
      for (int n = 0; n < 4; ++n) bfr[n] = *(const bf16x8*)(pb + (n << 10));
      if constexpr (BM == 256) {
#pragma unroll
        for (int m = 0; m < 4; ++m) ag[m] = *(const bf16x8*)(pa + 4096 + (m << 10));
      }
      if (half == 0) { stA(kt + 1, 1, nb); stB(kt + 1, 1, nb); }
      else           { stA(kt + 2, 0, b);  stB(kt + 2, 0, b);  }
      __builtin_amdgcn_s_setprio(1);
#pragma unroll
      for (int m = 0; m < 4; ++m)
#pragma unroll
        for (int n = 0; n < 4; ++n)
          acc[m][n] = __builtin_amdgcn_mfma_f32_16x16x32_bf16(af[m], bfr[n], acc[m][n], 0, 0, 0);
      if constexpr (BM == 256) {
#pragma unroll
        for (int m = 0; m < 4; ++m)
#pragma unroll
          for (int n = 0; n < 4; ++n)
            acc[4 + m][n] = __builtin_amdgcn_mfma_f32_16x16x32_bf16(ag[m], bfr[n], acc[4 + m][n], 0, 0, 0);
      }
      __builtin_amdgcn_s_setprio(0);
    }
  }

#pragma unroll
  for (int mf = 0; mf < MF; ++mf) {
    const int rb = row0 + wm * (BM / 2) + (mf >> 2) * 64 + (mf & 3) * 16 + (l4 << 2);
#pragma unroll
    for (int reg = 0; reg < 4; ++reg) {
      TC* crow = C + (size_t)(rb + reg) * N + col0 + (wn << 6) + l15;
#pragma unroll
      for (int n = 0; n < 4; ++n) st1(crow + (n << 4), acc[mf][n][reg]);
    }
  }
}

// ---------------------------------------------------------------------------
// V-transpose only (norm/rope fused into gemm_qkv's epilogue).
// ---------------------------------------------------------------------------
__global__ __launch_bounds__(256)
void v_transpose(const __bf16* __restrict__ qkv, __bf16* __restrict__ Vt) {
  __shared__ __bf16 tile[64][72];
  const int b   = blockIdx.x;               // 0..1023
  const int tid = threadIdx.x;
  const int tb  = (b & 63) * 64;
  const int yy  = b >> 6;                   // 0..15
  const int kvh = yy >> 2;
  const int db  = (yy & 3) * 64;
#pragma unroll
  for (int i = 0; i < 2; ++i) {
    const int s = i * 256 + tid;
    const int r = s >> 3, c = (s & 7) * 8;
    bf16x8 val = *(const bf16x8*)(qkv + (size_t)(tb + r) * 4096 + 3072 + kvh * HD + db + c);
#pragma unroll
    for (int j = 0; j < 8; ++j) tile[r][c + j] = val[j];
  }
  __syncthreads();
#pragma unroll
  for (int i = 0; i < 2; ++i) {
    const int s = i * 256 + tid;
    const int r = s >> 3, c = (s & 7) * 8;
    bf16x8 outv;
#pragma unroll
    for (int j = 0; j < 8; ++j) outv[j] = tile[c + j][r];
    *(bf16x8*)(Vt + (size_t)(kvh * HD + db + r) * SEQ + tb + c) = outv;
  }
}

// ---------------------------------------------------------------------------
// Sliding-window flash attention — r5 known-best structure, verbatim.
// ---------------------------------------------------------------------------
__global__ __launch_bounds__(256, 2)
void attn_fwd(const __bf16* __restrict__ qkv, const __bf16* __restrict__ Vt,
              __bf16* __restrict__ Y) {
  __shared__ char klds[2][16384];      // [slot][32 key][32 dim] rows of 64B, swz
  __shared__ char vlds[2][16384];      // [slot][256 dim][32 key] rows of 64B, swz
  __shared__ __bf16 Ps[4][16][40];     // per-wave P (padded rows)
  const int tid  = threadIdx.x;
  const int lane = tid & 63;
  const int wave = tid >> 6;
  const int l15  = lane & 15;
  const int l4   = lane >> 4;
  const int lin  = blockIdx.x;
  const int head = lin & 7;            // head-per-XCD pinning
  const int q0   = (lin >> 3) * 64;
  const int kvh  = head >> 1;
  const int qw   = q0 + wave * 16;

  // Q fragments: A[m=lane&15][k=(lane>>4)*8+j]; pre-scale 1/16 (exact pow2)
  bf16x8 qf[8];
  const __bf16* qrow = qkv + (size_t)(qw + l15) * 4096 + head * HD;
#pragma unroll
  for (int ks = 0; ks < 8; ++ks) {
    bf16x8 t = *(const bf16x8*)(qrow + ks * 32 + l4 * 8);
#pragma unroll
    for (int j = 0; j < 8; ++j) t[j] = (__bf16)((float)t[j] * 0.0625f);
    qf[ks] = t;
  }

  f32x4 o[16] = {};
  float l_run[4] = {0.f, 0.f, 0.f, 0.f};

  int lo = q0 - (WIN - 1); if (lo < 0) lo = 0;
  const int kt0 = lo >> 5;
  const int kt1 = (q0 + 63) >> 5;      // >= kt0+1 always (>=2 tiles)
  const int kbmax = kt1 << 5;

  const int skey = (tid >> 2) & 31;                 // K: key row
  const int sdim = tid >> 2;                        // V: dim row (+ i*64)
  const int sg   = (tid & 3) ^ ((tid >> 3) & 3);    // swizzled source col16
  const int sth  = tid >> 7;

  auto stK = [&](int kt, int b) {
    int kb = kt << 5; if (kb > kbmax) kb = kbmax;   // clamped dummy re-issue
    const __bf16* s = qkv + (size_t)(kb + skey) * 4096 + 2048 + kvh * HD
                          + sth * 32 + sg * 8;
    char* d = klds[b] + wave * 1024;
#pragma unroll
    for (int i = 0; i < 4; ++i)
      gload16(s + i * 64, d + i * 4096);
  };
  auto stV = [&](int kt, int b) {
    int kb = kt << 5; if (kb > kbmax) kb = kbmax;
    const __bf16* s = Vt + ((size_t)kvh * HD + sdim) * SEQ + kb + sg * 8;
    char* d = vlds[b] + wave * 1024;
#pragma unroll
    for (int i = 0; i < 4; ++i)
      gload16(s + (size_t)i * 64 * SEQ, d + i * 4096);
  };

  stK(kt0, 0);     stV(kt0, 0);
  stK(kt0 + 1, 1); stV(kt0 + 1, 1);

  const int rswz = (l4 ^ ((l15 >> 1) & 3)) << 4;

  for (int kt = kt0; kt <= kt1; ++kt) {
    const int p  = (kt - kt0) & 1;
    const int kb = kt << 5;
    asm volatile("s_waitcnt vmcnt(8)" ::: "memory");
    barx();

    // S = (Q/16) K^T   (32 keys: kn = 0..1)
    const char* kbase = klds[p];
    f32x4 s_acc[2] = {};
    __builtin_amdgcn_s_setprio(1);
#pragma unroll
    for (int kn = 0; kn < 2; ++kn) {
#pragma unroll
      for (int ks = 0; ks < 8; ++ks) {
        bf16x8 kf = *(const bf16x8*)(kbase + (ks * 32 + kn * 16 + l15) * 64 + rswz);
        s_acc[kn] = __builtin_amdgcn_mfma_f32_16x16x32_bf16(qf[ks], kf, s_acc[kn], 0, 0, 0);
      }
    }
    __builtin_amdgcn_s_setprio(0);

    // fixed-max softmax: p = exp(min(s,34)-34); masked -> 0
    // Fast path (wave-uniform): tile fully inside causal+window.
    if ((kb + 31 <= qw) && (kb >= qw - 1008)) {
#pragma unroll
      for (int reg = 0; reg < 4; ++reg) {
        const int r = l4 * 4 + reg;
        float ps = 0.f;
#pragma unroll
        for (int kn = 0; kn < 2; ++kn) {
          const float pv = __expf(fminf(s_acc[kn][reg], 34.f) - 34.f);
          ps += pv;
          Ps[wave][r][kn * 16 + l15] = (__bf16)pv;
        }
        l_run[reg] += ps;
      }
    } else {
#pragma unroll
      for (int reg = 0; reg < 4; ++reg) {
        const int r  = l4 * 4 + reg;
        const int qg = qw + r;
        float ps = 0.f;
#pragma unroll
        for (int kn = 0; kn < 2; ++kn) {
          const int kg = kb + kn * 16 + l15;
          const bool ok = (kg <= qg) && (kg > qg - WIN);
          const float pv = ok ? __expf(fminf(s_acc[kn][reg], 34.f) - 34.f) : 0.f;
          ps += pv;
          Ps[wave][r][kn * 16 + l15] = (__bf16)pv;
        }
        l_run[reg] += ps;
      }
    }

    // O += P V   (Ps per-wave; intra-wave LDS ordering needs no barrier)
    const char* vbase = vlds[p];
    bf16x8 pf = *(const bf16x8*)&Ps[wave][l15][l4 * 8];
    __builtin_amdgcn_s_setprio(1);
#pragma unroll
    for (int dn = 0; dn < 16; ++dn) {
      bf16x8 vf = *(const bf16x8*)(vbase + (dn * 16 + l15) * 64 + rswz);
      o[dn] = __builtin_amdgcn_mfma_f32_16x16x32_bf16(pf, vf, o[dn], 0, 0, 0);
    }
    __builtin_amdgcn_s_setprio(0);

    // retire buf p readers, then refill it with tile kt+2
    barx();
    stK(kt + 2, p);
    stV(kt + 2, p);
  }
  // no DMA in flight at exit (LDS may be reassigned to the next block)
  asm volatile("s_waitcnt vmcnt(0)" ::: "memory");

  // epilogue: reduce l across the 16 lanes sharing each row, then scale
#pragma unroll
  for (int reg = 0; reg < 4; ++reg) {
#pragma unroll
    for (int off = 1; off < 16; off <<= 1)
      l_run[reg] += __shfl_xor(l_run[reg], off);
    const float inv = 1.0f / l_run[reg];
    const int q = qw + l4 * 4 + reg;
    __bf16* yrow = Y + ((size_t)q * NH + head) * HD + l15;
#pragma unroll
    for (int dn = 0; dn < 16; ++dn)
      yrow[dn * 16] = (__bf16)(o[dn][reg] * inv);
  }
}

// ---------------------------------------------------------------------------
extern "C" void kernel_launch(void* const* d_in, const int* in_sizes, int n_in,
                              void* d_out, int out_size, void* d_ws, size_t ws_size,
                              hipStream_t stream) {
  (void)in_sizes; (void)n_in; (void)out_size; (void)ws_size;
  const float* x   = (const float*)d_in[0];
  const int*   pos = (const int*)d_in[1];
  const float* Wq  = (const float*)d_in[2];
  const float* Wk  = (const float*)d_in[3];
  const float* Wv  = (const float*)d_in[4];
  const float* Wo  = (const float*)d_in[5];
  const float* qw  = (const float*)d_in[6];
  const float* kw  = (const float*)d_in[7];
  float* out = (float*)d_out;

  char* ws = (char*)d_ws;
  const size_t MB = 1024 * 1024;
  __bf16* qkv_ws = (__bf16*)(ws);             // 32 MiB  [4096][4096]
  __bf16* vt_ws  = (__bf16*)(ws + 32 * MB);   //  8 MiB  [4][256][4096]
  __bf16* y_ws   = (__bf16*)(ws + 40 * MB);   // 16 MiB  [4096][2048]
  __bf16* xb     = (__bf16*)(ws + 56 * MB);   // 16 MiB
  __bf16* wqkvb  = (__bf16*)(ws + 72 * MB);   // 16 MiB  [4096][2048]
  __bf16* wob    = (__bf16*)(ws + 88 * MB);   //  8 MiB  (total 96 MiB)

  cvt_all<<<dim3(10240), dim3(256), 0, stream>>>(x, Wq, Wk, Wv, Wo, xb, wqkvb, wob);
  gemm_qkv<<<dim3(256), dim3(512), 0, stream>>>(xb, wqkvb, qkv_ws, qw, kw, pos, 4096, 2048);
  v_transpose<<<dim3(1024), dim3(256), 0, stream>>>(qkv_ws, vt_ws);
  attn_fwd<<<dim3(512), dim3(256), 0, stream>>>(qkv_ws, vt_ws, y_ws);
  gemm2ph<128, float><<<dim3(256), dim3(512), 0, stream>>>(y_ws, wob, out, 2048, 2048);
}

// Round 11
// 312.519 us; speedup vs baseline: 1.1209x; 1.1156x over previous
//
#include <hip/hip_runtime.h>
#include <cstdint>
#include <cmath>

typedef __bf16 bf16x8 __attribute__((ext_vector_type(8)));
typedef float  f32x4  __attribute__((ext_vector_type(4)));

#define DEVI __device__ __forceinline__

#define SEQ 4096
#define NH 8
#define NKV 4
#define HD 256
#define WIN 1024

DEVI void gload16(const void* g, void* l) {
  __builtin_amdgcn_global_load_lds((const __attribute__((address_space(1))) void*)g,
                                   (__attribute__((address_space(3))) void*)l,
                                   16, 0, 0);
}

DEVI bf16x8 ld8f(const float* p) {
  const f32x4 a = *(const f32x4*)p;
  const f32x4 b = *(const f32x4*)(p + 4);
  bf16x8 r;
#pragma unroll
  for (int j = 0; j < 4; ++j) { r[j] = (__bf16)a[j]; r[4 + j] = (__bf16)b[j]; }
  return r;
}

DEVI void st1(float* p, float v)  { *p = v; }
DEVI void st1(__bf16* p, float v) { *p = (__bf16)v; }

// raw barrier (no vmcnt(0) drain, unlike __syncthreads) + compiler memory fence
DEVI void barx() {
  asm volatile("" ::: "memory");
  __builtin_amdgcn_s_barrier();
  asm volatile("" ::: "memory");
}

// ---------------------------------------------------------------------------
// fp32 -> bf16 conversion. Wq/Wk/Wv concatenated into one 4096x2048 buffer.
// ---------------------------------------------------------------------------
__global__ __launch_bounds__(256)
void cvt_all(const float* __restrict__ x,  const float* __restrict__ wq,
             const float* __restrict__ wk, const float* __restrict__ wv,
             const float* __restrict__ wo,
             __bf16* __restrict__ xb, __bf16* __restrict__ wqkvb,
             __bf16* __restrict__ wob) {
  const size_t g = (size_t)blockIdx.x * 256 + threadIdx.x;
  const float* src; __bf16* dst; size_t off;
  if      (g < 1048576) { src = x;  dst = xb;               off = g; }
  else if (g < 1572864) { src = wq; dst = wqkvb;            off = g - 1048576; }
  else if (g < 1835008) { src = wk; dst = wqkvb + 4194304;  off = g - 1572864; }
  else if (g < 2097152) { src = wv; dst = wqkvb + 6291456;  off = g - 1835008; }
  else                  { src = wo; dst = wob;              off = g - 2097152; }
  *(bf16x8*)(dst + off * 8) = ld8f(src + off * 8);
}

// ---------------------------------------------------------------------------
// QKV GEMM + fused RMSNorm/RoPE epilogue.
// K-loop = validated gemm256<256> 4-phase schedule (r3-r8), UNTOUCHED.
// r10 post-mortem: store-burst reorder changed nothing (WRITE still 164MB) ->
// RMW theory falsified. New diagnosis: libm sincosf (out-pointer form) keeps
// its results in SCRATCH -> ~8B write + read-back per call x 12.6M calls
// ~= the 131MB excess; corroborated by the 192us MfmaUtil~0 first dispatch
// (scratch-buffer setup). Fix: native trig — v_sin/v_cos take REVOLUTIONS
// with fract-reduction (ISA §3), no pointers, no libm, no scratch:
//   xr = p * (inv_freq/2pi); xf = xr - floor(xr); s=sin(xf), c=cos(xf).
// ---------------------------------------------------------------------------
__global__ __launch_bounds__(512, 2)
void gemm_qkv(const __bf16* __restrict__ A, const __bf16* __restrict__ B,
              __bf16* __restrict__ C, const float* __restrict__ qnw,
              const float* __restrict__ knw, const int* __restrict__ pos,
              int N, int K) {
  constexpr int MF    = 8;
  constexpr int MH    = 4;
  constexpr int AUNIT = 16384;         // 256 rows * 64 B
  constexpr int ASZ   = 4 * AUNIT;
  constexpr int VMC   = 8;             // 2*AI + 4, AI = 2
  __shared__ char lds[ASZ + 65536];

  const int tid  = threadIdx.x;
  const int lane = tid & 63;
  const int wave = tid >> 6;
  const int l15  = lane & 15;
  const int l4   = lane >> 4;
  const int wm   = wave >> 2;
  const int wn   = wave & 3;

  const int lin  = blockIdx.x;
  const int xcd  = lin & 7;
  const int kk   = lin >> 3;
  const int nTn  = N >> 8;
  const int rowT = kk % 16;
  const int colT = xcd * (nTn >> 3) + kk / 16;
  const int row0 = rowT * 256;
  const int col0 = colT << 8;

  const int srow = tid >> 2;
  const int scol = ((tid & 3) ^ ((tid >> 3) & 3)) << 3;
  const __bf16* Asrc = A + (size_t)(row0 + srow) * K + scol;
  const __bf16* Bsrc = B + (size_t)(col0 + srow) * K + scol;

  const int swz  = (l4 ^ ((l15 >> 1) & 3)) << 4;
  const int aoff = (wm * 128 + l15) * 64 + swz;
  const int boff = ((wn << 6) + l15) * 64 + swz;

  auto stA = [&](int kx, int h) {
    int k0 = kx << 6; if (k0 >= K) k0 = 0;
    const __bf16* s = Asrc + k0 + (h << 5);
    char* d = lds + ((kx & 1) * 2 + h) * AUNIT + wave * 1024;
#pragma unroll
    for (int i = 0; i < 2; ++i)
      gload16(s + (size_t)(i << 7) * K, d + i * 8192);
  };
  auto stB = [&](int kx, int h) {
    int k0 = kx << 6; if (k0 >= K) k0 = 0;
    const __bf16* s = Bsrc + k0 + (h << 5);
    char* d = lds + ASZ + ((kx & 1) * 2 + h) * 16384 + wave * 1024;
#pragma unroll
    for (int i = 0; i < 2; ++i)
      gload16(s + (size_t)(i << 7) * K, d + i * 8192);
  };

  f32x4 acc[MF][4] = {};

  stA(0, 0); stB(0, 0); stA(0, 1); stB(0, 1); stA(1, 0); stB(1, 0);
  asm volatile("s_waitcnt vmcnt(%0)" :: "i"(VMC) : "memory");
  barx();

  const int NT = K >> 6;
  for (int kt = 0; kt < NT; ++kt) {
    const int bb = (kt & 1) * 2;
    bf16x8 bfr[4];
    bf16x8 af[MH];

    auto rd = [&](int h, int mg, bool readB) {
      const char* pa = lds + (bb + h) * AUNIT + aoff;
#pragma unroll
      for (int m = 0; m < MH; ++m)
        af[m] = *(const bf16x8*)(pa + ((mg * MH + m) << 10));
      if (readB) {
        const char* pb = lds + ASZ + (bb + h) * 16384 + boff;
#pragma unroll
        for (int n = 0; n < 4; ++n)
          bfr[n] = *(const bf16x8*)(pb + (n << 10));
      }
    };
    auto mm = [&](int mg) {
      barx();
      __builtin_amdgcn_s_setprio(1);
#pragma unroll
      for (int m = 0; m < MH; ++m)
#pragma unroll
        for (int n = 0; n < 4; ++n)
          acc[mg * MH + m][n] =
              __builtin_amdgcn_mfma_f32_16x16x32_bf16(af[m], bfr[n], acc[mg * MH + m][n], 0, 0, 0);
      __builtin_amdgcn_s_setprio(0);
    };

    // p0
    rd(0, 0, true);
    stA(kt + 1, 1);
    mm(0);
    // p1
    rd(0, 1, false);
    stB(kt + 1, 1);
    asm volatile("s_waitcnt vmcnt(%0)" :: "i"(VMC) : "memory");
    mm(1);
    // p2
    rd(1, 0, true);
    stA(kt + 2, 0);
    mm(0);
    // p3
    rd(1, 1, false);
    stB(kt + 2, 0);
    asm volatile("s_waitcnt vmcnt(%0)" :: "i"(VMC) : "memory");
    mm(1);
  }
  asm volatile("s_waitcnt vmcnt(0)" ::: "memory");

  if (colT < 12) {
    // ---- fused RMSNorm + RoPE (Q: colT<8 with qnw, K: 8..11 with knw) ----
    barx();                                    // LDS free for reuse (see hdr)
    float* ssb = (float*)lds;                  // [256 rows][4 wn]
#pragma unroll
    for (int mf = 0; mf < MF; ++mf) {
#pragma unroll
      for (int reg = 0; reg < 4; ++reg) {
        float q = 0.f;
#pragma unroll
        for (int n = 0; n < 4; ++n) { const float v = acc[mf][n][reg]; q += v * v; }
        q += __shfl_xor(q, 1); q += __shfl_xor(q, 2);
        q += __shfl_xor(q, 4); q += __shfl_xor(q, 8);
        if (l15 == 0) {
          const int lr = wm * 128 + (mf >> 2) * 64 + (mf & 3) * 16 + (l4 << 2) + reg;
          ssb[lr * 4 + wn] = q;
        }
      }
    }
    barx();
    const float* w = (colT < 8) ? qnw : knw;
    float wv4[4], fr2[4];
#pragma unroll
    for (int n = 0; n < 4; ++n) {
      const int d = (wn << 6) + n * 16 + l15;  // head dim of this element
      wv4[n] = w[d];
      // inv_freq(d&127) / 2pi  -> angle in REVOLUTIONS per unit position
      fr2[n] = exp2f(-(float)(d & 127) * 0.103810253f) * 0.15915494f;
    }
    const float sgn = (l15 & 1) ? 1.f : -1.f;  // even d: -x[d+1]; odd: +x[d-1]
#pragma unroll
    for (int mf = 0; mf < MF; ++mf) {
#pragma unroll
      for (int reg = 0; reg < 4; ++reg) {
        const int lr = wm * 128 + (mf >> 2) * 64 + (mf & 3) * 16 + (l4 << 2) + reg;
        const float ss = ssb[lr * 4 + 0] + ssb[lr * 4 + 1]
                       + ssb[lr * 4 + 2] + ssb[lr * 4 + 3];
        const float rms = rsqrtf(ss * (1.0f / 256.0f) + 1e-6f);
        const float p = (float)pos[row0 + lr];
        float ov[4];
#pragma unroll
        for (int n = 0; n < 4; ++n) {
          const float nv = acc[mf][n][reg] * rms * wv4[n];
          const float pk = __shfl_xor(nv, 1);  // partner dim d^1, same row
          // native trig: revolutions + fract reduction, no libm/scratch
          const float xr = p * fr2[n];
          const float xf = xr - floorf(xr);
          const float s  = __builtin_amdgcn_sinf(xf);
          const float c  = __builtin_amdgcn_cosf(xf);
          ov[n] = nv * c + sgn * pk * s;
        }
        __bf16* crow = C + (size_t)(row0 + lr) * N + col0 + (wn << 6) + l15;
#pragma unroll
        for (int n = 0; n < 4; ++n) crow[n * 16] = (__bf16)ov[n];
      }
    }
  } else {
    // ---- V band: plain store (transposed later by v_transpose) ----
#pragma unroll
    for (int mf = 0; mf < MF; ++mf) {
      const int rb = row0 + wm * 128 + (mf >> 2) * 64 + (mf & 3) * 16 + (l4 << 2);
#pragma unroll
      for (int reg = 0; reg < 4; ++reg) {
        __bf16* crow = C + (size_t)(rb + reg) * N + col0 + (wn << 6) + l15;
#pragma unroll
        for (int n = 0; n < 4; ++n) crow[n << 4] = (__bf16)acc[mf][n][reg];
      }
    }
  }
}

// ---------------------------------------------------------------------------
// GEMM 2-phase — out-proj (BM=128). Proven best in rounds 4/5 (~48 µs).
// ---------------------------------------------------------------------------
template <int BM, typename TC>
__global__ __launch_bounds__(512, 2)
void gemm2ph(const __bf16* __restrict__ A, const __bf16* __restrict__ B,
             TC* __restrict__ C, int N, int K) {
  constexpr int AI    = BM / 128;
  constexpr int MF    = BM / 32;
  constexpr int AUNIT = BM * 64;
  constexpr int ASZ   = 4 * AUNIT;
  constexpr int VMC   = 2 * (AI + 2);
  __shared__ char lds[ASZ + 65536];

  const int tid  = threadIdx.x;
  const int lane = tid & 63;
  const int wave = tid >> 6;
  const int l15  = lane & 15;
  const int l4   = lane >> 4;
  const int wm   = wave >> 2;
  const int wn   = wave & 3;

  constexpr int nTm = 4096 / BM;
  const int lin  = blockIdx.x;
  const int xcd  = lin & 7;
  const int kk   = lin >> 3;
  const int nTn  = N >> 8;
  const int rowT = kk % nTm;
  const int colT = xcd * (nTn >> 3) + kk / nTm;
  const int row0 = rowT * BM;
  const int col0 = colT << 8;

  const int srow = tid >> 2;
  const int scol = ((tid & 3) ^ ((tid >> 3) & 3)) << 3;
  const __bf16* Asrc = A + (size_t)(row0 + srow) * K + scol;
  const __bf16* Bsrc = B + (size_t)(col0 + srow) * K + scol;

  const int swz  = (l4 ^ ((l15 >> 1) & 3)) << 4;
  const int aoff = (wm * (BM / 2) + l15) * 64 + swz;
  const int boff = ((wn << 6) + l15) * 64 + swz;

  auto stA = [&](int kx, int h, int b) {
    int k0 = kx << 6; if (k0 >= K) k0 = 0;
    const __bf16* s = Asrc + k0 + (h << 5);
    char* d = lds + (b * 2 + h) * AUNIT + wave * 1024;
#pragma unroll
    for (int i = 0; i < AI; ++i)
      gload16(s + (size_t)(i << 7) * K, d + i * 8192);
  };
  auto stB = [&](int kx, int h, int b) {
    int k0 = kx << 6; if (k0 >= K) k0 = 0;
    const __bf16* s = Bsrc + k0 + (h << 5);
    char* d = lds + ASZ + (b * 2 + h) * 16384 + wave * 1024;
#pragma unroll
    for (int i = 0; i < 2; ++i)
      gload16(s + (size_t)(i << 7) * K, d + i * 8192);
  };

  f32x4 acc[MF][4] = {};

  stA(0, 0, 0); stB(0, 0, 0);
  stA(0, 1, 0); stB(0, 1, 0);
  stA(1, 0, 1); stB(1, 0, 1);

  const int NT = K >> 6;
  for (int kt = 0; kt < NT; ++kt) {
    const int b = kt & 1, nb = b ^ 1;
#pragma unroll
    for (int half = 0; half < 2; ++half) {
      asm volatile("s_waitcnt vmcnt(%0)" :: "i"(VMC) : "memory");
      barx();
      bf16x8 af[4], ag[4], bfr[4];
      const char* pa = lds + (b * 2 + half) * AUNIT + aoff;
      const char* pb = lds + ASZ + (b * 2 + half) * 16384 + boff;
#pragma unroll
      for (int m = 0; m < 4; ++m) af[m] = *(const bf16x8*)(pa + (m << 10));
#pragma unroll
      for (int n = 0; n < 4; ++n) bfr[n] = *(const bf16x8*)(pb + (n << 10));
      if constexpr (BM == 256) {
#pragma unroll
        for (int m = 0; m < 4; ++m) ag[m] = *(const bf16x8*)(pa + 4096 + (m << 10));
      }
      if (half == 0) { stA(kt + 1, 1, nb); stB(kt + 1, 1, nb); }
      else           { stA(kt + 2, 0, b);  stB(kt + 2, 0, b);  }
      __builtin_amdgcn_s_setprio(1);
#pragma unroll
      for (int m = 0; m < 4; ++m)
#pragma unroll
        for (int n = 0; n < 4; ++n)
          acc[m][n] = __builtin_amdgcn_mfma_f32_16x16x32_bf16(af[m], bfr[n], acc[m][n], 0, 0, 0);
      if constexpr (BM == 256) {
#pragma unroll
        for (int m = 0; m < 4; ++m)
#pragma unroll
          for (int n = 0; n < 4; ++n)
            acc[4 + m][n] = __builtin_amdgcn_mfma_f32_16x16x32_bf16(ag[m], bfr[n], acc[4 + m][n], 0, 0, 0);
      }
      __builtin_amdgcn_s_setprio(0);
    }
  }

#pragma unroll
  for (int mf = 0; mf < MF; ++mf) {
    const int rb = row0 + wm * (BM / 2) + (mf >> 2) * 64 + (mf & 3) * 16 + (l4 << 2);
#pragma unroll
    for (int reg = 0; reg < 4; ++reg) {
      TC* crow = C + (size_t)(rb + reg) * N + col0 + (wn << 6) + l15;
#pragma unroll
      for (int n = 0; n < 4; ++n) st1(crow + (n << 4), acc[mf][n][reg]);
    }
  }
}

// ---------------------------------------------------------------------------
// V-transpose only (norm/rope fused into gemm_qkv's epilogue).
// ---------------------------------------------------------------------------
__global__ __launch_bounds__(256)
void v_transpose(const __bf16* __restrict__ qkv, __bf16* __restrict__ Vt) {
  __shared__ __bf16 tile[64][72];
  const int b   = blockIdx.x;               // 0..1023
  const int tid = threadIdx.x;
  const int tb  = (b & 63) * 64;
  const int yy  = b >> 6;                   // 0..15
  const int kvh = yy >> 2;
  const int db  = (yy & 3) * 64;
#pragma unroll
  for (int i = 0; i < 2; ++i) {
    const int s = i * 256 + tid;
    const int r = s >> 3, c = (s & 7) * 8;
    bf16x8 val = *(const bf16x8*)(qkv + (size_t)(tb + r) * 4096 + 3072 + kvh * HD + db + c);
#pragma unroll
    for (int j = 0; j < 8; ++j) tile[r][c + j] = val[j];
  }
  __syncthreads();
#pragma unroll
  for (int i = 0; i < 2; ++i) {
    const int s = i * 256 + tid;
    const int r = s >> 3, c = (s & 7) * 8;
    bf16x8 outv;
#pragma unroll
    for (int j = 0; j < 8; ++j) outv[j] = tile[c + j][r];
    *(bf16x8*)(Vt + (size_t)(kvh * HD + db + r) * SEQ + tb + c) = outv;
  }
}

// ---------------------------------------------------------------------------
// Sliding-window flash attention — r5 known-best structure, verbatim.
// ---------------------------------------------------------------------------
__global__ __launch_bounds__(256, 2)
void attn_fwd(const __bf16* __restrict__ qkv, const __bf16* __restrict__ Vt,
              __bf16* __restrict__ Y) {
  __shared__ char klds[2][16384];      // [slot][32 key][32 dim] rows of 64B, swz
  __shared__ char vlds[2][16384];      // [slot][256 dim][32 key] rows of 64B, swz
  __shared__ __bf16 Ps[4][16][40];     // per-wave P (padded rows)
  const int tid  = threadIdx.x;
  const int lane = tid & 63;
  const int wave = tid >> 6;
  const int l15  = lane & 15;
  const int l4   = lane >> 4;
  const int lin  = blockIdx.x;
  const int head = lin & 7;            // head-per-XCD pinning
  const int q0   = (lin >> 3) * 64;
  const int kvh  = head >> 1;
  const int qw   = q0 + wave * 16;

  // Q fragments: A[m=lane&15][k=(lane>>4)*8+j]; pre-scale 1/16 (exact pow2)
  bf16x8 qf[8];
  const __bf16* qrow = qkv + (size_t)(qw + l15) * 4096 + head * HD;
#pragma unroll
  for (int ks = 0; ks < 8; ++ks) {
    bf16x8 t = *(const bf16x8*)(qrow + ks * 32 + l4 * 8);
#pragma unroll
    for (int j = 0; j < 8; ++j) t[j] = (__bf16)((float)t[j] * 0.0625f);
    qf[ks] = t;
  }

  f32x4 o[16] = {};
  float l_run[4] = {0.f, 0.f, 0.f, 0.f};

  int lo = q0 - (WIN - 1); if (lo < 0) lo = 0;
  const int kt0 = lo >> 5;
  const int kt1 = (q0 + 63) >> 5;      // >= kt0+1 always (>=2 tiles)
  const int kbmax = kt1 << 5;

  const int skey = (tid >> 2) & 31;                 // K: key row
  const int sdim = tid >> 2;                        // V: dim row (+ i*64)
  const int sg   = (tid & 3) ^ ((tid >> 3) & 3);    // swizzled source col16
  const int sth  = tid >> 7;

  auto stK = [&](int kt, int b) {
    int kb = kt << 5; if (kb > kbmax) kb = kbmax;   // clamped dummy re-issue
    const __bf16* s = qkv + (size_t)(kb + skey) * 4096 + 2048 + kvh * HD
                          + sth * 32 + sg * 8;
    char* d = klds[b] + wave * 1024;
#pragma unroll
    for (int i = 0; i < 4; ++i)
      gload16(s + i * 64, d + i * 4096);
  };
  auto stV = [&](int kt, int b) {
    int kb = kt << 5; if (kb > kbmax) kb = kbmax;
    const __bf16* s = Vt + ((size_t)kvh * HD + sdim) * SEQ + kb + sg * 8;
    char* d = vlds[b] + wave * 1024;
#pragma unroll
    for (int i = 0; i < 4; ++i)
      gload16(s + (size_t)i * 64 * SEQ, d + i * 4096);
  };

  stK(kt0, 0);     stV(kt0, 0);
  stK(kt0 + 1, 1); stV(kt0 + 1, 1);

  const int rswz = (l4 ^ ((l15 >> 1) & 3)) << 4;

  for (int kt = kt0; kt <= kt1; ++kt) {
    const int p  = (kt - kt0) & 1;
    const int kb = kt << 5;
    asm volatile("s_waitcnt vmcnt(8)" ::: "memory");
    barx();

    // S = (Q/16) K^T   (32 keys: kn = 0..1)
    const char* kbase = klds[p];
    f32x4 s_acc[2] = {};
    __builtin_amdgcn_s_setprio(1);
#pragma unroll
    for (int kn = 0; kn < 2; ++kn) {
#pragma unroll
      for (int ks = 0; ks < 8; ++ks) {
        bf16x8 kf = *(const bf16x8*)(kbase + (ks * 32 + kn * 16 + l15) * 64 + rswz);
        s_acc[kn] = __builtin_amdgcn_mfma_f32_16x16x32_bf16(qf[ks], kf, s_acc[kn], 0, 0, 0);
      }
    }
    __builtin_amdgcn_s_setprio(0);

    // fixed-max softmax: p = exp(min(s,34)-34); masked -> 0
    // Fast path (wave-uniform): tile fully inside causal+window.
    if ((kb + 31 <= qw) && (kb >= qw - 1008)) {
#pragma unroll
      for (int reg = 0; reg < 4; ++reg) {
        const int r = l4 * 4 + reg;
        float ps = 0.f;
#pragma unroll
        for (int kn = 0; kn < 2; ++kn) {
          const float pv = __expf(fminf(s_acc[kn][reg], 34.f) - 34.f);
          ps += pv;
          Ps[wave][r][kn * 16 + l15] = (__bf16)pv;
        }
        l_run[reg] += ps;
      }
    } else {
#pragma unroll
      for (int reg = 0; reg < 4; ++reg) {
        const int r  = l4 * 4 + reg;
        const int qg = qw + r;
        float ps = 0.f;
#pragma unroll
        for (int kn = 0; kn < 2; ++kn) {
          const int kg = kb + kn * 16 + l15;
          const bool ok = (kg <= qg) && (kg > qg - WIN);
          const float pv = ok ? __expf(fminf(s_acc[kn][reg], 34.f) - 34.f) : 0.f;
          ps += pv;
          Ps[wave][r][kn * 16 + l15] = (__bf16)pv;
        }
        l_run[reg] += ps;
      }
    }

    // O += P V   (Ps per-wave; intra-wave LDS ordering needs no barrier)
    const char* vbase = vlds[p];
    bf16x8 pf = *(const bf16x8*)&Ps[wave][l15][l4 * 8];
    __builtin_amdgcn_s_setprio(1);
#pragma unroll
    for (int dn = 0; dn < 16; ++dn) {
      bf16x8 vf = *(const bf16x8*)(vbase + (dn * 16 + l15) * 64 + rswz);
      o[dn] = __builtin_amdgcn_mfma_f32_16x16x32_bf16(pf, vf, o[dn], 0, 0, 0);
    }
    __builtin_amdgcn_s_setprio(0);

    // retire buf p readers, then refill it with tile kt+2
    barx();
    stK(kt + 2, p);
    stV(kt + 2, p);
  }
  // no DMA in flight at exit (LDS may be reassigned to the next block)
  asm volatile("s_waitcnt vmcnt(0)" ::: "memory");

  // epilogue: reduce l across the 16 lanes sharing each row, then scale
#pragma unroll
  for (int reg = 0; reg < 4; ++reg) {
#pragma unroll
    for (int off = 1; off < 16; off <<= 1)
      l_run[reg] += __shfl_xor(l_run[reg], off);
    const float inv = 1.0f / l_run[reg];
    const int q = qw + l4 * 4 + reg;
    __bf16* yrow = Y + ((size_t)q * NH + head) * HD + l15;
#pragma unroll
    for (int dn = 0; dn < 16; ++dn)
      yrow[dn * 16] = (__bf16)(o[dn][reg] * inv);
  }
}

// ---------------------------------------------------------------------------
extern "C" void kernel_launch(void* const* d_in, const int* in_sizes, int n_in,
                              void* d_out, int out_size, void* d_ws, size_t ws_size,
                              hipStream_t stream) {
  (void)in_sizes; (void)n_in; (void)out_size; (void)ws_size;
  const float* x   = (const float*)d_in[0];
  const int*   pos = (const int*)d_in[1];
  const float* Wq  = (const float*)d_in[2];
  const float* Wk  = (const float*)d_in[3];
  const float* Wv  = (const float*)d_in[4];
  const float* Wo  = (const float*)d_in[5];
  const float* qw  = (const float*)d_in[6];
  const float* kw  = (const float*)d_in[7];
  float* out = (float*)d_out;

  char* ws = (char*)d_ws;
  const size_t MB = 1024 * 1024;
  __bf16* qkv_ws = (__bf16*)(ws);             // 32 MiB  [4096][4096]
  __bf16* vt_ws  = (__bf16*)(ws + 32 * MB);   //  8 MiB  [4][256][4096]
  __bf16* y_ws   = (__bf16*)(ws + 40 * MB);   // 16 MiB  [4096][2048]
  __bf16* xb     = (__bf16*)(ws + 56 * MB);   // 16 MiB
  __bf16* wqkvb  = (__bf16*)(ws + 72 * MB);   // 16 MiB  [4096][2048]
  __bf16* wob    = (__bf16*)(ws + 88 * MB);   //  8 MiB  (total 96 MiB)

  cvt_all<<<dim3(10240), dim3(256), 0, stream>>>(x, Wq, Wk, Wv, Wo, xb, wqkvb, wob);
  gemm_qkv<<<dim3(256), dim3(512), 0, stream>>>(xb, wqkvb, qkv_ws, qw, kw, pos, 4096, 2048);
  v_transpose<<<dim3(1024), dim3(256), 0, stream>>>(qkv_ws, vt_ws);
  attn_fwd<<<dim3(512), dim3(256), 0, stream>>>(qkv_ws, vt_ws, y_ws);
  gemm2ph<128, float><<<dim3(256), dim3(512), 0, stream>>>(y_ws, wob, out, 2048, 2048);
}

// Round 13
// 303.183 us; speedup vs baseline: 1.1554x; 1.0308x over previous
//
#include <hip/hip_runtime.h>
#include <cstdint>
#include <cmath>

typedef __bf16 bf16x8 __attribute__((ext_vector_type(8)));
typedef float  f32x4  __attribute__((ext_vector_type(4)));

#define DEVI __device__ __forceinline__

#define SEQ 4096
#define NH 8
#define NKV 4
#define HD 256
#define WIN 1024

DEVI void gload16(const void* g, void* l) {
  __builtin_amdgcn_global_load_lds((const __attribute__((address_space(1))) void*)g,
                                   (__attribute__((address_space(3))) void*)l,
                                   16, 0, 0);
}

DEVI bf16x8 ld8f(const float* p) {
  const f32x4 a = *(const f32x4*)p;
  const f32x4 b = *(const f32x4*)(p + 4);
  bf16x8 r;
#pragma unroll
  for (int j = 0; j < 4; ++j) { r[j] = (__bf16)a[j]; r[4 + j] = (__bf16)b[j]; }
  return r;
}

DEVI void st1(float* p, float v)  { *p = v; }
DEVI void st1(__bf16* p, float v) { *p = (__bf16)v; }

// raw barrier (no vmcnt(0) drain, unlike __syncthreads) + compiler memory fence
DEVI void barx() {
  asm volatile("" ::: "memory");
  __builtin_amdgcn_s_barrier();
  asm volatile("" ::: "memory");
}

// ---------------------------------------------------------------------------
// fp32 -> bf16 conversion. Wq/Wk/Wv concatenated into one 4096x2048 buffer.
// ---------------------------------------------------------------------------
__global__ __launch_bounds__(256)
void cvt_all(const float* __restrict__ x,  const float* __restrict__ wq,
             const float* __restrict__ wk, const float* __restrict__ wv,
             const float* __restrict__ wo,
             __bf16* __restrict__ xb, __bf16* __restrict__ wqkvb,
             __bf16* __restrict__ wob) {
  const size_t g = (size_t)blockIdx.x * 256 + threadIdx.x;
  const float* src; __bf16* dst; size_t off;
  if      (g < 1048576) { src = x;  dst = xb;               off = g; }
  else if (g < 1572864) { src = wq; dst = wqkvb;            off = g - 1048576; }
  else if (g < 1835008) { src = wk; dst = wqkvb + 4194304;  off = g - 1572864; }
  else if (g < 2097152) { src = wv; dst = wqkvb + 6291456;  off = g - 1835008; }
  else                  { src = wo; dst = wob;              off = g - 2097152; }
  *(bf16x8*)(dst + off * 8) = ld8f(src + off * 8);
}

// ---------------------------------------------------------------------------
// GEMM (BM=256): m201-style 4-phase fine interleave per K-tile.
// Validated rounds 3-8 (~65 µs, MfmaUtil ~44%). The r9-r11 fused-epilogue
// variant was structurally unprofitable (serial shuffle/trig tail with 1
// block/CU cost +38 µs > the ~20 µs standalone norm kernel) — reverted.
// ---------------------------------------------------------------------------
template <int BM, typename TC>
__global__ __launch_bounds__(512, 2)
void gemm256(const __bf16* __restrict__ A, const __bf16* __restrict__ B,
             TC* __restrict__ C, int N, int K) {
  constexpr int AI    = BM / 128;
  constexpr int MF    = BM / 32;
  constexpr int MH    = MF / 2;
  constexpr int AUNIT = BM * 64;
  constexpr int ASZ   = 4 * AUNIT;
  constexpr int VMC   = 2 * AI + 4;
  __shared__ char lds[ASZ + 65536];

  const int tid  = threadIdx.x;
  const int lane = tid & 63;
  const int wave = tid >> 6;
  const int l15  = lane & 15;
  const int l4   = lane >> 4;
  const int wm   = wave >> 2;
  const int wn   = wave & 3;

  constexpr int nTm = 4096 / BM;
  const int lin  = blockIdx.x;
  const int xcd  = lin & 7;
  const int kk   = lin >> 3;
  const int nTn  = N >> 8;
  const int rowT = kk % nTm;
  const int colT = xcd * (nTn >> 3) + kk / nTm;
  const int row0 = rowT * BM;
  const int col0 = colT << 8;

  const int srow = tid >> 2;
  const int scol = ((tid & 3) ^ ((tid >> 3) & 3)) << 3;
  const __bf16* Asrc = A + (size_t)(row0 + srow) * K + scol;
  const __bf16* Bsrc = B + (size_t)(col0 + srow) * K + scol;

  const int swz  = (l4 ^ ((l15 >> 1) & 3)) << 4;
  const int aoff = (wm * (BM / 2) + l15) * 64 + swz;
  const int boff = ((wn << 6) + l15) * 64 + swz;

  auto stA = [&](int kx, int h) {
    int k0 = kx << 6; if (k0 >= K) k0 = 0;
    const __bf16* s = Asrc + k0 + (h << 5);
    char* d = lds + ((kx & 1) * 2 + h) * AUNIT + wave * 1024;
#pragma unroll
    for (int i = 0; i < AI; ++i)
      gload16(s + (size_t)(i << 7) * K, d + i * 8192);
  };
  auto stB = [&](int kx, int h) {
    int k0 = kx << 6; if (k0 >= K) k0 = 0;
    const __bf16* s = Bsrc + k0 + (h << 5);
    char* d = lds + ASZ + ((kx & 1) * 2 + h) * 16384 + wave * 1024;
#pragma unroll
    for (int i = 0; i < 2; ++i)
      gload16(s + (size_t)(i << 7) * K, d + i * 8192);
  };

  f32x4 acc[MF][4] = {};

  stA(0, 0); stB(0, 0); stA(0, 1); stB(0, 1); stA(1, 0); stB(1, 0);
  asm volatile("s_waitcnt vmcnt(%0)" :: "i"(VMC) : "memory");
  barx();

  const int NT = K >> 6;
  for (int kt = 0; kt < NT; ++kt) {
    const int bb = (kt & 1) * 2;
    bf16x8 bfr[4];
    bf16x8 af[MH];

    auto rd = [&](int h, int mg, bool readB) {
      const char* pa = lds + (bb + h) * AUNIT + aoff;
#pragma unroll
      for (int m = 0; m < MH; ++m)
        af[m] = *(const bf16x8*)(pa + ((mg * MH + m) << 10));
      if (readB) {
        const char* pb = lds + ASZ + (bb + h) * 16384 + boff;
#pragma unroll
        for (int n = 0; n < 4; ++n)
          bfr[n] = *(const bf16x8*)(pb + (n << 10));
      }
    };
    auto mm = [&](int mg) {
      barx();
      __builtin_amdgcn_s_setprio(1);
#pragma unroll
      for (int m = 0; m < MH; ++m)
#pragma unroll
        for (int n = 0; n < 4; ++n)
          acc[mg * MH + m][n] =
              __builtin_amdgcn_mfma_f32_16x16x32_bf16(af[m], bfr[n], acc[mg * MH + m][n], 0, 0, 0);
      __builtin_amdgcn_s_setprio(0);
    };

    // p0
    rd(0, 0, true);
    stA(kt + 1, 1);
    mm(0);
    // p1
    rd(0, 1, false);
    stB(kt + 1, 1);
    asm volatile("s_waitcnt vmcnt(%0)" :: "i"(VMC) : "memory");
    mm(1);
    // p2
    rd(1, 0, true);
    stA(kt + 2, 0);
    mm(0);
    // p3
    rd(1, 1, false);
    stB(kt + 2, 0);
    asm volatile("s_waitcnt vmcnt(%0)" :: "i"(VMC) : "memory");
    mm(1);
  }
  asm volatile("s_waitcnt vmcnt(0)" ::: "memory");

#pragma unroll
  for (int mf = 0; mf < MF; ++mf) {
    const int rb = row0 + wm * (BM / 2) + (mf >> 2) * 64 + (mf & 3) * 16 + (l4 << 2);
#pragma unroll
    for (int reg = 0; reg < 4; ++reg) {
      TC* crow = C + (size_t)(rb + reg) * N + col0 + (wn << 6) + l15;
#pragma unroll
      for (int n = 0; n < 4; ++n) st1(crow + (n << 4), acc[mf][n][reg]);
    }
  }
}

// ---------------------------------------------------------------------------
// GEMM 2-phase — out-proj (BM=128). Proven best in rounds 4/5 (~48 µs).
// ---------------------------------------------------------------------------
template <int BM, typename TC>
__global__ __launch_bounds__(512, 2)
void gemm2ph(const __bf16* __restrict__ A, const __bf16* __restrict__ B,
             TC* __restrict__ C, int N, int K) {
  constexpr int AI    = BM / 128;
  constexpr int MF    = BM / 32;
  constexpr int AUNIT = BM * 64;
  constexpr int ASZ   = 4 * AUNIT;
  constexpr int VMC   = 2 * (AI + 2);
  __shared__ char lds[ASZ + 65536];

  const int tid  = threadIdx.x;
  const int lane = tid & 63;
  const int wave = tid >> 6;
  const int l15  = lane & 15;
  const int l4   = lane >> 4;
  const int wm   = wave >> 2;
  const int wn   = wave & 3;

  constexpr int nTm = 4096 / BM;
  const int lin  = blockIdx.x;
  const int xcd  = lin & 7;
  const int kk   = lin >> 3;
  const int nTn  = N >> 8;
  const int rowT = kk % nTm;
  const int colT = xcd * (nTn >> 3) + kk / nTm;
  const int row0 = rowT * BM;
  const int col0 = colT << 8;

  const int srow = tid >> 2;
  const int scol = ((tid & 3) ^ ((tid >> 3) & 3)) << 3;
  const __bf16* Asrc = A + (size_t)(row0 + srow) * K + scol;
  const __bf16* Bsrc = B + (size_t)(col0 + srow) * K + scol;

  const int swz  = (l4 ^ ((l15 >> 1) & 3)) << 4;
  const int aoff = (wm * (BM / 2) + l15) * 64 + swz;
  const int boff = ((wn << 6) + l15) * 64 + swz;

  auto stA = [&](int kx, int h, int b) {
    int k0 = kx << 6; if (k0 >= K) k0 = 0;
    const __bf16* s = Asrc + k0 + (h << 5);
    char* d = lds + (b * 2 + h) * AUNIT + wave * 1024;
#pragma unroll
    for (int i = 0; i < AI; ++i)
      gload16(s + (size_t)(i << 7) * K, d + i * 8192);
  };
  auto stB = [&](int kx, int h, int b) {
    int k0 = kx << 6; if (k0 >= K) k0 = 0;
    const __bf16* s = Bsrc + k0 + (h << 5);
    char* d = lds + ASZ + (b * 2 + h) * 16384 + wave * 1024;
#pragma unroll
    for (int i = 0; i < 2; ++i)
      gload16(s + (size_t)(i << 7) * K, d + i * 8192);
  };

  f32x4 acc[MF][4] = {};

  stA(0, 0, 0); stB(0, 0, 0);
  stA(0, 1, 0); stB(0, 1, 0);
  stA(1, 0, 1); stB(1, 0, 1);

  const int NT = K >> 6;
  for (int kt = 0; kt < NT; ++kt) {
    const int b = kt & 1, nb = b ^ 1;
#pragma unroll
    for (int half = 0; half < 2; ++half) {
      asm volatile("s_waitcnt vmcnt(%0)" :: "i"(VMC) : "memory");
      barx();
      bf16x8 af[4], ag[4], bfr[4];
      const char* pa = lds + (b * 2 + half) * AUNIT + aoff;
      const char* pb = lds + ASZ + (b * 2 + half) * 16384 + boff;
#pragma unroll
      for (int m = 0; m < 4; ++m) af[m] = *(const bf16x8*)(pa + (m << 10));
#pragma unroll
      for (int n = 0; n < 4; ++n) bfr[n] = *(const bf16x8*)(pb + (n << 10));
      if constexpr (BM == 256) {
#pragma unroll
        for (int m = 0; m < 4; ++m) ag[m] = *(const bf16x8*)(pa + 4096 + (m << 10));
      }
      if (half == 0) { stA(kt + 1, 1, nb); stB(kt + 1, 1, nb); }
      else           { stA(kt + 2, 0, b);  stB(kt + 2, 0, b);  }
      __builtin_amdgcn_s_setprio(1);
#pragma unroll
      for (int m = 0; m < 4; ++m)
#pragma unroll
        for (int n = 0; n < 4; ++n)
          acc[m][n] = __builtin_amdgcn_mfma_f32_16x16x32_bf16(af[m], bfr[n], acc[m][n], 0, 0, 0);
      if constexpr (BM == 256) {
#pragma unroll
        for (int m = 0; m < 4; ++m)
#pragma unroll
          for (int n = 0; n < 4; ++n)
            acc[4 + m][n] = __builtin_amdgcn_mfma_f32_16x16x32_bf16(ag[m], bfr[n], acc[4 + m][n], 0, 0, 0);
      }
      __builtin_amdgcn_s_setprio(0);
    }
  }

#pragma unroll
  for (int mf = 0; mf < MF; ++mf) {
    const int rb = row0 + wm * (BM / 2) + (mf >> 2) * 64 + (mf & 3) * 16 + (l4 << 2);
#pragma unroll
    for (int reg = 0; reg < 4; ++reg) {
      TC* crow = C + (size_t)(rb + reg) * N + col0 + (wn << 6) + l15;
#pragma unroll
      for (int n = 0; n < 4; ++n) st1(crow + (n << 4), acc[mf][n][reg]);
    }
  }
}

// ---------------------------------------------------------------------------
// Merged: per-head RMSNorm+RoPE (blocks 0..12287) and V-transpose (12288+).
// r12: libm sincosf replaced by native revolution-trig (v_sin/v_cos with
// fract reduction) — r11 proved sincosf's out-pointer form bounces through
// SCRATCH (~13+ µs of hidden TCC traffic for the same 12.6M calls here);
// the native formula was numerically verified in r11 (passed, same absmax).
// ---------------------------------------------------------------------------
__global__ __launch_bounds__(256)
void norm_rope_tv(__bf16* __restrict__ qkv, __bf16* __restrict__ Vt,
                  const float* __restrict__ qw, const float* __restrict__ kw,
                  const int* __restrict__ pos) {
  if (blockIdx.x < 12288) {
    const int gw   = blockIdx.x * 4 + (threadIdx.x >> 6);
    const int lane = threadIdx.x & 63;
    __bf16* base; const float* w; int t;
    if (gw < SEQ * NH) {
      t = gw >> 3;
      base = qkv + (size_t)t * 4096 + (gw & 7) * HD;
      w = qw;
    } else {
      const int g = gw - SEQ * NH;
      t = g >> 2;
      base = qkv + (size_t)t * 4096 + 2048 + (g & 3) * HD;
      w = kw;
    }

    const int d0 = lane * 4;
    float v[4]; float ss = 0.f;
#pragma unroll
    for (int j = 0; j < 4; ++j) { v[j] = (float)base[d0 + j]; ss += v[j] * v[j]; }
#pragma unroll
    for (int off = 1; off < 64; off <<= 1) ss += __shfl_xor(ss, off);
    const float rms = rsqrtf(ss * (1.0f / 256.0f) + 1e-6f);
    const float p = (float)pos[t];

    float n[4];
#pragma unroll
    for (int j = 0; j < 4; ++j) n[j] = v[j] * rms * w[d0 + j];

    float outv[4];
#pragma unroll
    for (int e = 0; e < 4; e += 2) {
      const int i0 = d0 + e, i1 = i0 + 1;
      // angle in REVOLUTIONS (inv_freq / 2pi); fract-reduce; native v_sin/cos
      const float fr0 = exp2f(-(float)(i0 & 127) * 0.103810253f) * 0.15915494f;
      const float fr1 = exp2f(-(float)(i1 & 127) * 0.103810253f) * 0.15915494f;
      float x0 = p * fr0; x0 -= floorf(x0);
      float x1 = p * fr1; x1 -= floorf(x1);
      const float s0  = __builtin_amdgcn_sinf(x0);
      const float cc0 = __builtin_amdgcn_cosf(x0);
      const float s1  = __builtin_amdgcn_sinf(x1);
      const float cc1 = __builtin_amdgcn_cosf(x1);
      outv[e]     = n[e] * cc0 - n[e + 1] * s0;
      outv[e + 1] = n[e + 1] * cc1 + n[e] * s1;
    }
#pragma unroll
    for (int j = 0; j < 4; ++j) base[d0 + j] = (__bf16)outv[j];
  } else {
    __shared__ __bf16 tile[64][72];
    const int b   = blockIdx.x - 12288;       // 0..1023
    const int tid = threadIdx.x;
    const int tb  = (b & 63) * 64;
    const int yy  = b >> 6;                   // 0..15
    const int kvh = yy >> 2;
    const int db  = (yy & 3) * 64;
#pragma unroll
    for (int i = 0; i < 2; ++i) {
      const int s = i * 256 + tid;
      const int r = s >> 3, c = (s & 7) * 8;
      bf16x8 val = *(const bf16x8*)(qkv + (size_t)(tb + r) * 4096 + 3072 + kvh * HD + db + c);
#pragma unroll
      for (int j = 0; j < 8; ++j) tile[r][c + j] = val[j];
    }
    __syncthreads();
#pragma unroll
    for (int i = 0; i < 2; ++i) {
      const int s = i * 256 + tid;
      const int r = s >> 3, c = (s & 7) * 8;
      bf16x8 outv;
#pragma unroll
      for (int j = 0; j < 8; ++j) outv[j] = tile[c + j][r];
      *(bf16x8*)(Vt + (size_t)(kvh * HD + db + r) * SEQ + tb + c) = outv;
    }
  }
}

// ---------------------------------------------------------------------------
// Sliding-window flash attention — r5 known-best structure, verbatim
// (2-slot dbuf, vmcnt(8) gate, T2 swizzle, head-per-XCD, fast-path softmax;
// measured 64.4-65.1 µs across r5/r6/r8).
// ---------------------------------------------------------------------------
__global__ __launch_bounds__(256, 2)
void attn_fwd(const __bf16* __restrict__ qkv, const __bf16* __restrict__ Vt,
              __bf16* __restrict__ Y) {
  __shared__ char klds[2][16384];      // [slot][32 key][32 dim] rows of 64B, swz
  __shared__ char vlds[2][16384];      // [slot][256 dim][32 key] rows of 64B, swz
  __shared__ __bf16 Ps[4][16][40];     // per-wave P (padded rows)
  const int tid  = threadIdx.x;
  const int lane = tid & 63;
  const int wave = tid >> 6;
  const int l15  = lane & 15;
  const int l4   = lane >> 4;
  const int lin  = blockIdx.x;
  const int head = lin & 7;            // head-per-XCD pinning
  const int q0   = (lin >> 3) * 64;
  const int kvh  = head >> 1;
  const int qw   = q0 + wave * 16;

  // Q fragments: A[m=lane&15][k=(lane>>4)*8+j]; pre-scale 1/16 (exact pow2)
  bf16x8 qf[8];
  const __bf16* qrow = qkv + (size_t)(qw + l15) * 4096 + head * HD;
#pragma unroll
  for (int ks = 0; ks < 8; ++ks) {
    bf16x8 t = *(const bf16x8*)(qrow + ks * 32 + l4 * 8);
#pragma unroll
    for (int j = 0; j < 8; ++j) t[j] = (__bf16)((float)t[j] * 0.0625f);
    qf[ks] = t;
  }

  f32x4 o[16] = {};
  float l_run[4] = {0.f, 0.f, 0.f, 0.f};

  int lo = q0 - (WIN - 1); if (lo < 0) lo = 0;
  const int kt0 = lo >> 5;
  const int kt1 = (q0 + 63) >> 5;      // >= kt0+1 always (>=2 tiles)
  const int kbmax = kt1 << 5;

  const int skey = (tid >> 2) & 31;                 // K: key row
  const int sdim = tid >> 2;                        // V: dim row (+ i*64)
  const int sg   = (tid & 3) ^ ((tid >> 3) & 3);    // swizzled source col16
  const int sth  = tid >> 7;

  auto stK = [&](int kt, int b) {
    int kb = kt << 5; if (kb > kbmax) kb = kbmax;   // clamped dummy re-issue
    const __bf16* s = qkv + (size_t)(kb + skey) * 4096 + 2048 + kvh * HD
                          + sth * 32 + sg * 8;
    char* d = klds[b] + wave * 1024;
#pragma unroll
    for (int i = 0; i < 4; ++i)
      gload16(s + i * 64, d + i * 4096);
  };
  auto stV = [&](int kt, int b) {
    int kb = kt << 5; if (kb > kbmax) kb = kbmax;
    const __bf16* s = Vt + ((size_t)kvh * HD + sdim) * SEQ + kb + sg * 8;
    char* d = vlds[b] + wave * 1024;
#pragma unroll
    for (int i = 0; i < 4; ++i)
      gload16(s + (size_t)i * 64 * SEQ, d + i * 4096);
  };

  stK(kt0, 0);     stV(kt0, 0);
  stK(kt0 + 1, 1); stV(kt0 + 1, 1);

  const int rswz = (l4 ^ ((l15 >> 1) & 3)) << 4;

  for (int kt = kt0; kt <= kt1; ++kt) {
    const int p  = (kt - kt0) & 1;
    const int kb = kt << 5;
    asm volatile("s_waitcnt vmcnt(8)" ::: "memory");
    barx();

    // S = (Q/16) K^T   (32 keys: kn = 0..1)
    const char* kbase = klds[p];
    f32x4 s_acc[2] = {};
    __builtin_amdgcn_s_setprio(1);
#pragma unroll
    for (int kn = 0; kn < 2; ++kn) {
#pragma unroll
      for (int ks = 0; ks < 8; ++ks) {
        bf16x8 kf = *(const bf16x8*)(kbase + (ks * 32 + kn * 16 + l15) * 64 + rswz);
        s_acc[kn] = __builtin_amdgcn_mfma_f32_16x16x32_bf16(qf[ks], kf, s_acc[kn], 0, 0, 0);
      }
    }
    __builtin_amdgcn_s_setprio(0);

    // fixed-max softmax: p = exp(min(s,34)-34); masked -> 0
    // Fast path (wave-uniform): tile fully inside causal+window.
    if ((kb + 31 <= qw) && (kb >= qw - 1008)) {
#pragma unroll
      for (int reg = 0; reg < 4; ++reg) {
        const int r = l4 * 4 + reg;
        float ps = 0.f;
#pragma unroll
        for (int kn = 0; kn < 2; ++kn) {
          const float pv = __expf(fminf(s_acc[kn][reg], 34.f) - 34.f);
          ps += pv;
          Ps[wave][r][kn * 16 + l15] = (__bf16)pv;
        }
        l_run[reg] += ps;
      }
    } else {
#pragma unroll
      for (int reg = 0; reg < 4; ++reg) {
        const int r  = l4 * 4 + reg;
        const int qg = qw + r;
        float ps = 0.f;
#pragma unroll
        for (int kn = 0; kn < 2; ++kn) {
          const int kg = kb + kn * 16 + l15;
          const bool ok = (kg <= qg) && (kg > qg - WIN);
          const float pv = ok ? __expf(fminf(s_acc[kn][reg], 34.f) - 34.f) : 0.f;
          ps += pv;
          Ps[wave][r][kn * 16 + l15] = (__bf16)pv;
        }
        l_run[reg] += ps;
      }
    }

    // O += P V   (Ps per-wave; intra-wave LDS ordering needs no barrier)
    const char* vbase = vlds[p];
    bf16x8 pf = *(const bf16x8*)&Ps[wave][l15][l4 * 8];
    __builtin_amdgcn_s_setprio(1);
#pragma unroll
    for (int dn = 0; dn < 16; ++dn) {
      bf16x8 vf = *(const bf16x8*)(vbase + (dn * 16 + l15) * 64 + rswz);
      o[dn] = __builtin_amdgcn_mfma_f32_16x16x32_bf16(pf, vf, o[dn], 0, 0, 0);
    }
    __builtin_amdgcn_s_setprio(0);

    // retire buf p readers, then refill it with tile kt+2
    barx();
    stK(kt + 2, p);
    stV(kt + 2, p);
  }
  // no DMA in flight at exit (LDS may be reassigned to the next block)
  asm volatile("s_waitcnt vmcnt(0)" ::: "memory");

  // epilogue: reduce l across the 16 lanes sharing each row, then scale
#pragma unroll
  for (int reg = 0; reg < 4; ++reg) {
#pragma unroll
    for (int off = 1; off < 16; off <<= 1)
      l_run[reg] += __shfl_xor(l_run[reg], off);
    const float inv = 1.0f / l_run[reg];
    const int q = qw + l4 * 4 + reg;
    __bf16* yrow = Y + ((size_t)q * NH + head) * HD + l15;
#pragma unroll
    for (int dn = 0; dn < 16; ++dn)
      yrow[dn * 16] = (__bf16)(o[dn][reg] * inv);
  }
}

// ---------------------------------------------------------------------------
extern "C" void kernel_launch(void* const* d_in, const int* in_sizes, int n_in,
                              void* d_out, int out_size, void* d_ws, size_t ws_size,
                              hipStream_t stream) {
  (void)in_sizes; (void)n_in; (void)out_size; (void)ws_size;
  const float* x   = (const float*)d_in[0];
  const int*   pos = (const int*)d_in[1];
  const float* Wq  = (const float*)d_in[2];
  const float* Wk  = (const float*)d_in[3];
  const float* Wv  = (const float*)d_in[4];
  const float* Wo  = (const float*)d_in[5];
  const float* qw  = (const float*)d_in[6];
  const float* kw  = (const float*)d_in[7];
  float* out = (float*)d_out;

  char* ws = (char*)d_ws;
  const size_t MB = 1024 * 1024;
  __bf16* qkv_ws = (__bf16*)(ws);             // 32 MiB  [4096][4096]
  __bf16* vt_ws  = (__bf16*)(ws + 32 * MB);   //  8 MiB  [4][256][4096]
  __bf16* y_ws   = (__bf16*)(ws + 40 * MB);   // 16 MiB  [4096][2048]
  __bf16* xb     = (__bf16*)(ws + 56 * MB);   // 16 MiB
  __bf16* wqkvb  = (__bf16*)(ws + 72 * MB);   // 16 MiB  [4096][2048]
  __bf16* wob    = (__bf16*)(ws + 88 * MB);   //  8 MiB  (total 96 MiB)

  cvt_all<<<dim3(10240), dim3(256), 0, stream>>>(x, Wq, Wk, Wv, Wo, xb, wqkvb, wob);
  gemm256<256, __bf16><<<dim3(256), dim3(512), 0, stream>>>(xb, wqkvb, qkv_ws, 4096, 2048);
  norm_rope_tv<<<dim3(13312), dim3(256), 0, stream>>>(qkv_ws, vt_ws, qw, kw, pos);
  attn_fwd<<<dim3(512), dim3(256), 0, stream>>>(qkv_ws, vt_ws, y_ws);
  gemm2ph<128, float><<<dim3(256), dim3(512), 0, stream>>>(y_ws, wob, out, 2048, 2048);
}